// Round 4
// baseline (634.074 us; speedup 1.0000x reference)
//
#include <hip/hip_runtime.h>
#include <math.h>

#define HH 2048
#define WW 2048
#define NPIX (HH*WW)
#define NP4  (NPIX/4)
#define MAXNC 100

// stats layout (floats; key regions reinterpreted as uint32)
#define S_AREA 0
#define S_SX   100
#define S_SY   200
#define S_SHOT 300
#define S_MUX  400
#define S_MUY  500
#define S_CXX  600
#define S_CXY  700
#define S_CYY  800
#define S_RC   900
#define S_RS   1000
#define S_MG   1100
#define S_KMINX 1200
#define S_KMAXX 1300
#define S_KMINY 1400
#define S_KMAXY 1500
#define S_TOT  1600

__device__ __forceinline__ unsigned int encf(float f){
  unsigned int u = __float_as_uint(f);
  return (u & 0x80000000u) ? ~u : (u | 0x80000000u);
}
__device__ __forceinline__ float decf(unsigned int k){
  return (k & 0x80000000u) ? __uint_as_float(k & 0x7fffffffu) : __uint_as_float(~k);
}

// bijective XCD swizzle (m204): blocks b with b%8==x land on XCD x (round-robin
// dispatch); give each XCD a CONTIGUOUS work range so its L2 holds its slab.
__device__ __forceinline__ int xcd_swz(int b, int nwg){
  int q = nwg >> 3, r = nwg & 7;
  int xcd = b & 7, o = b >> 3;
  return (xcd < r ? xcd*(q+1) : r*(q+1) + (xcd-r)*q) + o;
}

__device__ __forceinline__ float blockReduceSum(float v, float* sh){
  int t = threadIdx.x;
  __syncthreads();
  sh[t] = v; __syncthreads();
  for (int o = 128; o > 0; o >>= 1){ if (t < o) sh[t] += sh[t+o]; __syncthreads(); }
  float r = sh[0]; __syncthreads();
  return r;
}
__device__ __forceinline__ float blockReduceMin(float v, float* sh){
  int t = threadIdx.x;
  __syncthreads();
  sh[t] = v; __syncthreads();
  for (int o = 128; o > 0; o >>= 1){ if (t < o) sh[t] = fminf(sh[t], sh[t+o]); __syncthreads(); }
  float r = sh[0]; __syncthreads();
  return r;
}
__device__ __forceinline__ float blockReduceMax(float v, float* sh){
  int t = threadIdx.x;
  __syncthreads();
  sh[t] = v; __syncthreads();
  for (int o = 128; o > 0; o >>= 1){ if (t < o) sh[t] = fmaxf(sh[t], sh[t+o]); __syncthreads(); }
  float r = sh[0]; __syncthreads();
  return r;
}

// ---------------- CCL ----------------

// init labels + identity LUT + clear stats (fused)
__global__ void k_init(const float* __restrict__ hot, int* __restrict__ lab,
                       int* __restrict__ lut, float* __restrict__ st){
  int t = blockIdx.x*256 + threadIdx.x;
  if (t < NP4){
    float4 h = ((const float4*)hot)[t];
    int b = t*4;
    int4 L;
    L.x = (h.x > 0.3f) ? b+1 : 0;
    L.y = (h.y > 0.3f) ? b+2 : 0;
    L.z = (h.z > 0.3f) ? b+3 : 0;
    L.w = (h.w > 0.3f) ? b+4 : 0;
    ((int4*)lab)[t] = L;
    ((int4*)lut)[t] = make_int4(b, b+1, b+2, b+3);
  } else if (t == NP4){
    lut[NPIX] = NPIX;
  }
  if (t < S_TOT) st[t] = (t >= S_KMINX) ? -0.0f : 0.0f;  // -0.0f bits == encf(0.0f)
}

// 3x3 window max, vertical 4-row strip per thread: 6 independent int4 row loads
// (rows y-1..y+4 of one int4 column), x-halo via wave shuffle, horizontal
// sliding max computed ONCE per loaded row, vertical max per output row.
// Clamped duplicate samples are idempotent under max; labels>=0 matches 0-pad.
// UNIQ: round-1 labels are unique per pixel -> plain store instead of atomicMax.
template<bool UNIQ>
__global__ __launch_bounds__(256, 4) void k_scatter(const int* __restrict__ lab, int* __restrict__ lut){
  int wb = xcd_swz(blockIdx.x, gridDim.x);       // contiguous strips per XCD
  int t  = wb*256 + threadIdx.x;                 // 0..NPIX/16-1
  int ci = t & 511;                              // int4 column
  int yb = t >> 9;                               // 4-row group
  int y0 = yb << 2;
  int lane = threadIdx.x & 63;
  int x4 = ci << 2;
  const int4* lab4 = (const int4*)lab;
  int rows[6];
  rows[0] = (y0 > 0) ? y0-1 : 0;
  rows[1] = y0; rows[2] = y0+1; rows[3] = y0+2; rows[4] = y0+3;
  rows[5] = (y0+4 < HH) ? y0+4 : HH-1;
  int4 R[6];
  #pragma unroll
  for (int j = 0; j < 6; ++j) R[j] = lab4[(rows[j]<<9) + ci];
  int Lh[6], Rh[6];
  #pragma unroll
  for (int j = 0; j < 6; ++j){ Lh[j] = __shfl_up(R[j].w, 1); Rh[j] = __shfl_down(R[j].x, 1); }
  if (lane == 0){
    #pragma unroll
    for (int j = 0; j < 6; ++j) Lh[j] = (x4 > 0) ? lab[(rows[j]<<11) + x4-1] : R[j].x;
  }
  if (lane == 63){
    #pragma unroll
    for (int j = 0; j < 6; ++j) Rh[j] = (x4+4 < WW) ? lab[(rows[j]<<11) + x4+4] : R[j].w;
  }
  int4 H[6];
  #pragma unroll
  for (int j = 0; j < 6; ++j){
    H[j].x = max(max(Lh[j],  R[j].x), R[j].y);
    H[j].y = max(max(R[j].x, R[j].y), R[j].z);
    H[j].z = max(max(R[j].y, R[j].z), R[j].w);
    H[j].w = max(max(R[j].z, R[j].w), Rh[j]);
  }
  #pragma unroll
  for (int k = 0; k < 4; ++k){
    int m0 = max(H[k].x, max(H[k+1].x, H[k+2].x));
    int m1 = max(H[k].y, max(H[k+1].y, H[k+2].y));
    int m2 = max(H[k].z, max(H[k+1].z, H[k+2].z));
    int m3 = max(H[k].w, max(H[k+1].w, H[k+2].w));
    int4 B = R[k+1];                             // center row y0+k
    if (B.x != 0 && m0 > B.x){ if (UNIQ) lut[B.x] = m0; else atomicMax(&lut[B.x], m0); }
    if (B.y != 0 && m1 > B.y){ if (UNIQ) lut[B.y] = m1; else atomicMax(&lut[B.y], m1); }
    if (B.z != 0 && m2 > B.z){ if (UNIQ) lut[B.z] = m2; else atomicMax(&lut[B.z], m2); }
    if (B.w != 0 && m3 > B.w){ if (UNIQ) lut[B.w] = m3; else atomicMax(&lut[B.w], m3); }
  }
}

// Fused synchronous pointer passes: dst[i] = src^(HOPS+1)[i].
// XCD-swizzled so each XCD streams a contiguous ~2MB slab; the early gather
// hops (diagonal shift ~8KB/application) stay inside the slab -> L2 hits.
template<int HOPS>
__global__ void k_compress(const int* __restrict__ src, int* __restrict__ dst){
  int wb = xcd_swz(blockIdx.x, gridDim.x);
  int base = (wb*256 + threadIdx.x) * 4;
  if (base + 3 <= NPIX){
    int4 v = *(const int4*)(src + base);
    int j0 = v.x, j1 = v.y, j2 = v.z, j3 = v.w;
    for (int k = 0; k < HOPS; ++k){
      j0 = src[j0]; j1 = src[j1]; j2 = src[j2]; j3 = src[j3];
    }
    *(int4*)(dst + base) = make_int4(j0, j1, j2, j3);
  } else {
    for (int i = base; i <= NPIX; ++i){
      int j = src[i];
      for (int k = 0; k < HOPS; ++k) j = src[j];
      dst[i] = j;
    }
  }
}

__global__ void k_apply(int* __restrict__ lab, const int* __restrict__ lut){
  int t = blockIdx.x*256 + threadIdx.x;
  if (t >= NP4) return;
  int4 L = ((int4*)lab)[t];
  L.x = lut[L.x]; L.y = lut[L.y]; L.z = lut[L.z]; L.w = lut[L.w];
  ((int4*)lab)[t] = L;
}

// ---------------- rank relabel ----------------

__global__ void k_clear(int* __restrict__ pres){
  int t = blockIdx.x*256 + threadIdx.x;
  if (t < NP4) ((int4*)pres)[t] = make_int4(0,0,0,0);
  else if (t == NP4) pres[NPIX] = 0;
}

// round-3 apply fused with presence marking
__global__ void k_apply_mark(int* __restrict__ lab, const int* __restrict__ lut, int* __restrict__ pres){
  int t = blockIdx.x*256 + threadIdx.x;
  if (t >= NP4) return;
  int4 L = ((int4*)lab)[t];
  L.x = lut[L.x]; L.y = lut[L.y]; L.z = lut[L.z]; L.w = lut[L.w];
  ((int4*)lab)[t] = L;
  pres[L.x] = 1; pres[L.y] = 1; pres[L.z] = 1; pres[L.w] = 1;
}

__global__ void k_scan1(const int* __restrict__ pres, int* __restrict__ bsum){
  __shared__ int sh[256];
  int t = threadIdx.x;
  int base = blockIdx.x*4096 + t*16;
  int run = 0;
  if (base + 15 <= NPIX){
    const int4* p4 = (const int4*)(pres + base);
    #pragma unroll
    for (int k = 0; k < 4; ++k){ int4 v = p4[k]; run += v.x + v.y + v.z + v.w; }
  } else {
    for (int k = 0; k < 16; ++k){ int idx = base + k; if (idx <= NPIX) run += pres[idx]; }
  }
  sh[t] = run; __syncthreads();
  for (int o = 128; o > 0; o >>= 1){ if (t < o) sh[t] += sh[t+o]; __syncthreads(); }
  if (t == 0) bsum[blockIdx.x] = sh[0];
}

__global__ void k_scan2(int* __restrict__ bs, int nb){
  __shared__ int sh[1024];
  int t = threadIdx.x;
  int v = (t < nb) ? bs[t] : 0;
  sh[t] = v; __syncthreads();
  for (int o = 1; o < 1024; o <<= 1){
    int add = (t >= o) ? sh[t-o] : 0;
    __syncthreads();
    sh[t] += add;
    __syncthreads();
  }
  if (t < nb) bs[t] = (t == 0) ? 0 : sh[t-1];   // exclusive
  if (t == 1023 && nb > 1024) bs[1024] = sh[1023]; // nb <= 1025 here
}

__global__ void k_scan3(int* __restrict__ pres, const int* __restrict__ bsum){
  __shared__ int sh[256];
  int t = threadIdx.x;
  int base = blockIdx.x*4096 + t*16;
  int v[16];
  int run = 0;
  bool vec = (base + 15 <= NPIX);
  if (vec){
    const int4* p4 = (const int4*)(pres + base);
    #pragma unroll
    for (int k = 0; k < 4; ++k){
      int4 q = p4[k];
      run += q.x; v[4*k]   = run;
      run += q.y; v[4*k+1] = run;
      run += q.z; v[4*k+2] = run;
      run += q.w; v[4*k+3] = run;
    }
  } else {
    #pragma unroll
    for (int k = 0; k < 16; ++k){
      int idx = base + k;
      int x = (idx <= NPIX) ? pres[idx] : 0;
      run += x; v[k] = run;
    }
  }
  sh[t] = run; __syncthreads();
  for (int o = 1; o < 256; o <<= 1){
    int add = (t >= o) ? sh[t-o] : 0;
    __syncthreads();
    sh[t] += add;
    __syncthreads();
  }
  int offs = bsum[blockIdx.x] + sh[t] - run - 1;   // rank = inclusive cumsum - 1
  if (vec){
    int4* p4 = (int4*)(pres + base);
    #pragma unroll
    for (int k = 0; k < 4; ++k)
      p4[k] = make_int4(v[4*k]+offs, v[4*k+1]+offs, v[4*k+2]+offs, v[4*k+3]+offs);
  } else {
    for (int k = 0; k < 16; ++k){ int idx = base + k; if (idx <= NPIX) pres[idx] = v[k] + offs; }
  }
}

// ---------------- per-segment stats ----------------

// fused: segment-id relabel (rank clamp) + first-moment accumulation
__global__ void k_stats1(int* __restrict__ lab, const int* __restrict__ ranks,
                         const float* __restrict__ hot, float* __restrict__ st){
  __shared__ float sh[256];
  float a0 = 0.f, x0 = 0.f, y0 = 0.f, h0 = 0.f;
  int stride = gridDim.x * blockDim.x;
  for (int t = blockIdx.x*blockDim.x + threadIdx.x; t < NP4; t += stride){
    int4 L = ((int4*)lab)[t];
    float4 hq = ((const float4*)hot)[t];
    int p0 = t*4;
    float xb = (float)(p0 & (WW-1));
    float yf = (float)(p0 >> 11);
    int ls[4] = {L.x, L.y, L.z, L.w};
    float hs[4] = {hq.x, hq.y, hq.z, hq.w};
    #pragma unroll
    for (int j = 0; j < 4; ++j){
      int r = ranks[ls[j]];
      int s = (r >= MAXNC) ? 0 : r;
      ls[j] = s;
      float xf = xb + (float)j;
      if (s == 0){ a0 += 1.f; x0 += xf; y0 += yf; h0 += hs[j]; }
      else {
        atomicAdd(&st[S_AREA+s], 1.f);
        atomicAdd(&st[S_SX+s], xf);
        atomicAdd(&st[S_SY+s], yf);
        atomicAdd(&st[S_SHOT+s], hs[j]);
      }
    }
    ((int4*)lab)[t] = make_int4(ls[0], ls[1], ls[2], ls[3]);
  }
  a0 = blockReduceSum(a0, sh);
  x0 = blockReduceSum(x0, sh);
  y0 = blockReduceSum(y0, sh);
  h0 = blockReduceSum(h0, sh);
  if (threadIdx.x == 0){
    atomicAdd(&st[S_AREA], a0);
    atomicAdd(&st[S_SX], x0);
    atomicAdd(&st[S_SY], y0);
    atomicAdd(&st[S_SHOT], h0);
  }
}

__global__ void k_mu(float* __restrict__ st){
  int s = threadIdx.x;
  if (s < MAXNC){
    float a = st[S_AREA+s];
    st[S_MUX+s] = st[S_SX+s] / a;   // 0/0 -> NaN matches ref
    st[S_MUY+s] = st[S_SY+s] / a;
  }
}

__global__ void k_stats2(const int* __restrict__ lab, float* __restrict__ st){
  __shared__ float sh[256];
  float xx0 = 0.f, xy0 = 0.f, yy0 = 0.f;
  int stride = gridDim.x * blockDim.x;
  for (int t = blockIdx.x*blockDim.x + threadIdx.x; t < NP4; t += stride){
    int4 L = ((int4*)lab)[t];
    int p0 = t*4;
    float xb = (float)(p0 & (WW-1));
    float yf = (float)(p0 >> 11);
    int ls[4] = {L.x, L.y, L.z, L.w};
    #pragma unroll
    for (int j = 0; j < 4; ++j){
      int s = ls[j];
      float cx = xb + (float)j - st[S_MUX+s];
      float cy = yf - st[S_MUY+s];
      float pxx = cx*cx, pxy = cx*cy, pyy = cy*cy;
      if (s == 0){ xx0 += pxx; xy0 += pxy; yy0 += pyy; }
      else {
        atomicAdd(&st[S_CXX+s], pxx);
        atomicAdd(&st[S_CXY+s], pxy);
        atomicAdd(&st[S_CYY+s], pyy);
      }
    }
  }
  xx0 = blockReduceSum(xx0, sh);
  xy0 = blockReduceSum(xy0, sh);
  yy0 = blockReduceSum(yy0, sh);
  if (threadIdx.x == 0){
    atomicAdd(&st[S_CXX], xx0);
    atomicAdd(&st[S_CXY], xy0);
    atomicAdd(&st[S_CYY], yy0);
  }
}

__global__ void k_svd(float* __restrict__ st){
  int s = threadIdx.x;
  if (s >= MAXNC) return;
  float a = st[S_AREA+s];
  float vx  = st[S_CXX+s] / a;
  float vxy = st[S_CXY+s] / a;
  float vy  = st[S_CYY+s] / a;
  float theta = 0.5f * atan2f(2.0f*vxy, vx - vy);
  float c = cosf(theta), sn = sinf(theta);
  float tr = vx + vy;
  float d = (vx - vy)*(vx - vy) + 4.0f*vxy*vxy;
  float disc = fmaxf(d, 1e-12f);
  float sq = sqrtf(disc);
  float l2 = fmaxf((tr - sq)*0.5f, 0.0f);
  float margin = sqrtf(sqrtf(l2)) * 4.0f;   // sqrt(l[:,1]) * 4 * MAR, l = sqrt(eig)
  st[S_RC+s] = c;
  st[S_RS+s] = sn;
  st[S_MG+s] = margin;
}

__global__ void k_stats3(const int* __restrict__ lab, float* __restrict__ st){
  __shared__ float sh[256];
  unsigned int* ku = (unsigned int*)st;
  float mnx =  INFINITY, mxx = -INFINITY, mny =  INFINITY, mxy = -INFINITY;
  int stride = gridDim.x * blockDim.x;
  for (int t = blockIdx.x*blockDim.x + threadIdx.x; t < NP4; t += stride){
    int4 L = ((int4*)lab)[t];
    int p0 = t*4;
    float xb = (float)(p0 & (WW-1));
    float yf = (float)(p0 >> 11);
    int ls[4] = {L.x, L.y, L.z, L.w};
    #pragma unroll
    for (int j = 0; j < 4; ++j){
      int s = ls[j];
      float cx = xb + (float)j - st[S_MUX+s];
      float cy = yf - st[S_MUY+s];
      float c = st[S_RC+s], sn = st[S_RS+s];
      float rx =  c*cx + sn*cy;   // m^T @ coords
      float ry = -sn*cx + c*cy;
      if (s == 0){
        mnx = fminf(mnx, rx); mxx = fmaxf(mxx, rx);
        mny = fminf(mny, ry); mxy = fmaxf(mxy, ry);
      } else {
        atomicMin(&ku[S_KMINX+s], encf(rx));
        atomicMax(&ku[S_KMAXX+s], encf(rx));
        atomicMin(&ku[S_KMINY+s], encf(ry));
        atomicMax(&ku[S_KMAXY+s], encf(ry));
      }
    }
  }
  mnx = blockReduceMin(mnx, sh);
  mxx = blockReduceMax(mxx, sh);
  mny = blockReduceMin(mny, sh);
  mxy = blockReduceMax(mxy, sh);
  if (threadIdx.x == 0){
    atomicMin(&ku[S_KMINX], encf(mnx));
    atomicMax(&ku[S_KMAXX], encf(mxx));
    atomicMin(&ku[S_KMINY], encf(mny));
    atomicMax(&ku[S_KMAXY], encf(mxy));
  }
}

__global__ void k_final(const float* __restrict__ st, const float* __restrict__ scale, float* __restrict__ out){
  int s = threadIdx.x;
  if (s >= MAXNC) return;
  const unsigned int* ku = (const unsigned int*)st;
  float a   = st[S_AREA+s];
  float lvl = st[S_SHOT+s];
  float mg  = st[S_MG+s];
  float minx = decf(ku[S_KMINX+s]) - mg;   // key init enc(0) == clamp vs 0
  float maxx = decf(ku[S_KMAXX+s]) + mg;
  float miny = decf(ku[S_KMINY+s]) - mg;
  float maxy = decf(ku[S_KMAXY+s]) + mg;
  bool ok = (lvl/a > 0.7f) && (maxx - minx > 5.0f) && (maxy - miny > 5.0f);  // NaN -> false
  float c = st[S_RC+s], sn = st[S_RS+s];
  float mux = st[S_MUX+s], muy = st[S_MUY+s];
  float sc2 = scale[0] * 2.0f;
  float rxs[5] = {minx, maxx, maxx, minx, minx};
  float rys[5] = {miny, miny, maxy, maxy, miny};
  #pragma unroll
  for (int k = 0; k < 5; ++k){
    float X = c*rxs[k] - sn*rys[k] + mux;   // m @ rec + mu
    float Y = sn*rxs[k] + c*rys[k] + muy;
    out[s*10 + 2*k + 0] = ok ? X * sc2 : 0.0f;
    out[s*10 + 2*k + 1] = ok ? Y * sc2 : 0.0f;
  }
}

// ---------------- host ----------------

extern "C" void kernel_launch(void* const* d_in, const int* in_sizes, int n_in,
                              void* d_out, int out_size, void* d_ws, size_t ws_size,
                              hipStream_t stream) {
  const float* hot   = (const float*)d_in[0];
  const float* scale = (const float*)d_in[1];
  float* out = (float*)d_out;

  char* ws = (char*)d_ws;
  size_t off = 0;
  int* lab  = (int*)(ws + off); off += (size_t)NPIX * 4;
  int* lutA = (int*)(ws + off); off += (size_t)(NPIX + 64) * 4;
  int* lutB = (int*)(ws + off); off += (size_t)(NPIX + 64) * 4;
  int* bsum = (int*)(ws + off); off += 2048 * 4;
  float* st = (float*)(ws + off); off += S_TOT * 4;

  dim3 B(256);
  int g4  = (NP4 + 255) / 256;          // 4096  — NP4-range kernels
  int g4t = (NP4 + 256) / 256;          // 4097  — NP4+1 threads (tail element)
  int gS  = NPIX/16/256;                // 1024  — scatter (16 px/thread)

  k_init<<<g4t, B, 0, stream>>>(hot, lab, lutA, st);

  int* cur = lutA;
  int* alt = lutB;

  // round 1: scatter (unique labels) + lut^4096 = ((S^8)^8)^8)^8
  k_scatter<true ><<<gS, B, 0, stream>>>(lab, cur);
  for (int i = 0; i < 4; ++i){
    k_compress<7><<<g4t, B, 0, stream>>>(cur, alt);
    int* t = cur; cur = alt; alt = t;
  }
  k_apply<<<g4, B, 0, stream>>>(lab, cur);

  // round 2: scatter + lut^64 (one fused kernel; chains are short now)
  k_scatter<false><<<gS, B, 0, stream>>>(lab, cur);
  k_compress<63><<<g4t, B, 0, stream>>>(cur, alt);
  { int* t = cur; cur = alt; alt = t; }
  k_apply<<<g4, B, 0, stream>>>(lab, cur);

  // round 3: scatter + lut^8
  k_scatter<false><<<gS, B, 0, stream>>>(lab, cur);
  k_compress<7><<<g4t, B, 0, stream>>>(cur, alt);
  { int* t = cur; cur = alt; alt = t; }

  // rank relabel: round-3 apply fused with presence marking
  int* pres = alt;                      // the non-current lut buffer is free now
  k_clear<<<g4t, B, 0, stream>>>(pres);
  k_apply_mark<<<g4, B, 0, stream>>>(lab, cur, pres);
  int NB = (NPIX + 1 + 4095) / 4096;    // 1025
  k_scan1<<<NB, B, 0, stream>>>(pres, bsum);
  k_scan2<<<1, 1024, 0, stream>>>(bsum, NB);
  k_scan3<<<NB, B, 0, stream>>>(pres, bsum);

  // per-segment stats (seg relabel fused into stats1; clearstats fused into init)
  k_stats1<<<2048, B, 0, stream>>>(lab, pres, hot, st);
  k_mu<<<1, 128, 0, stream>>>(st);
  k_stats2<<<2048, B, 0, stream>>>(lab, st);
  k_svd<<<1, 128, 0, stream>>>(st);
  k_stats3<<<2048, B, 0, stream>>>(lab, st);
  k_final<<<1, 128, 0, stream>>>(st, scale, out);
}

// Round 5
// 553.179 us; speedup vs baseline: 1.1462x; 1.1462x over previous
//
#include <hip/hip_runtime.h>
#include <math.h>

#define HH 2048
#define WW 2048
#define NPIX (HH*WW)
#define NP4  (NPIX/4)
#define MAXNC 100

// stats layout (floats; key regions reinterpreted as uint32)
#define S_AREA 0
#define S_SX   100
#define S_SY   200
#define S_SHOT 300
#define S_MUX  400
#define S_MUY  500
#define S_CXX  600
#define S_CXY  700
#define S_CYY  800
#define S_RC   900
#define S_RS   1000
#define S_MG   1100
#define S_KMINX 1200
#define S_KMAXX 1300
#define S_KMINY 1400
#define S_KMAXY 1500
#define S_TOT  1600

__device__ __forceinline__ unsigned int encf(float f){
  unsigned int u = __float_as_uint(f);
  return (u & 0x80000000u) ? ~u : (u | 0x80000000u);
}
__device__ __forceinline__ float decf(unsigned int k){
  return (k & 0x80000000u) ? __uint_as_float(k & 0x7fffffffu) : __uint_as_float(~k);
}

// bijective XCD swizzle: round-robin block->XCD dispatch becomes a contiguous
// work range per XCD so its private L2 holds one slab.
__device__ __forceinline__ int xcd_swz(int b, int nwg){
  int q = nwg >> 3, r = nwg & 7;
  int xcd = b & 7, o = b >> 3;
  return (xcd < r ? xcd*(q+1) : r*(q+1) + (xcd-r)*q) + o;
}

__device__ __forceinline__ float blockReduceSum(float v, float* sh){
  int t = threadIdx.x;
  __syncthreads();
  sh[t] = v; __syncthreads();
  for (int o = 128; o > 0; o >>= 1){ if (t < o) sh[t] += sh[t+o]; __syncthreads(); }
  float r = sh[0]; __syncthreads();
  return r;
}
__device__ __forceinline__ float blockReduceMin(float v, float* sh){
  int t = threadIdx.x;
  __syncthreads();
  sh[t] = v; __syncthreads();
  for (int o = 128; o > 0; o >>= 1){ if (t < o) sh[t] = fminf(sh[t], sh[t+o]); __syncthreads(); }
  float r = sh[0]; __syncthreads();
  return r;
}
__device__ __forceinline__ float blockReduceMax(float v, float* sh){
  int t = threadIdx.x;
  __syncthreads();
  sh[t] = v; __syncthreads();
  for (int o = 128; o > 0; o >>= 1){ if (t < o) sh[t] = fmaxf(sh[t], sh[t+o]); __syncthreads(); }
  float r = sh[0]; __syncthreads();
  return r;
}

// ---------------- CCL ----------------

// 3x3-max scatter, one block per lut-position row (y), 8 positions/thread.
// Thread covers lut positions P..P+7 (P = y*2048 + t*8) == pixels P-1..P+6.
// Halo via 3 ALIGNED int4 loads per row (no shuffles/DS); L1 catches overlap.
// R1: labels computed from hot in-register (lab array not needed); lut written
//     DENSELY (identity-or-windowmax) -> full-line stores, no init pass needed.
// else: read lab; rare conditional atomicMax (only where window-max > label).
template<bool R1>
__global__ __launch_bounds__(256) void k_scatter_row(const float* __restrict__ hot,
                                                     const int* __restrict__ lab,
                                                     int* __restrict__ lut){
  int y  = xcd_swz(blockIdx.x, HH);
  int t  = threadIdx.x;
  int x0 = t << 3;                       // first normal pixel col (pixels x0-1..x0+6)
  int P  = (y << 11) + x0;               // first lut position
  int ci = t << 1;                       // aligned int4 col of x0
  int cim = (ci > 0) ? ci - 1 : 0;
  int rows3[3];
  rows3[0] = (y > 0) ? y-1 : 0;
  rows3[1] = y;
  rows3[2] = (y < HH-1) ? y+1 : HH-1;

  int c[3][10];                          // cols x0-2 .. x0+7 per row
  #pragma unroll
  for (int j = 0; j < 3; ++j){
    int rb = rows3[j] << 9;              // int4-row base
    if constexpr (R1){
      const float4* h4 = (const float4*)hot;
      float4 a = h4[rb + cim], b = h4[rb + ci], d = h4[rb + ci + 1];
      int lb = rows3[j]*WW + (x0 - 2) + 1;    // label of col x0-2
      c[j][0] = (a.z > 0.3f) ? lb   : 0;
      c[j][1] = (a.w > 0.3f) ? lb+1 : 0;
      c[j][2] = (b.x > 0.3f) ? lb+2 : 0;
      c[j][3] = (b.y > 0.3f) ? lb+3 : 0;
      c[j][4] = (b.z > 0.3f) ? lb+4 : 0;
      c[j][5] = (b.w > 0.3f) ? lb+5 : 0;
      c[j][6] = (d.x > 0.3f) ? lb+6 : 0;
      c[j][7] = (d.y > 0.3f) ? lb+7 : 0;
      c[j][8] = (d.z > 0.3f) ? lb+8 : 0;
      c[j][9] = (d.w > 0.3f) ? lb+9 : 0;
    } else {
      const int4* l4 = (const int4*)lab;
      int4 a = l4[rb + cim], b = l4[rb + ci], d = l4[rb + ci + 1];
      c[j][0] = a.z; c[j][1] = a.w;
      c[j][2] = b.x; c[j][3] = b.y; c[j][4] = b.z; c[j][5] = b.w;
      c[j][6] = d.x; c[j][7] = d.y; c[j][8] = d.z; c[j][9] = d.w;
    }
    if (t == 0){ c[j][0] = c[j][2]; c[j][1] = c[j][2]; }  // clamp cols -2,-1 -> col 0
  }

  int m[8];
  #pragma unroll
  for (int k = 0; k < 8; ++k){
    int h0 = max(max(c[0][k], c[0][k+1]), c[0][k+2]);
    int h1 = max(max(c[1][k], c[1][k+1]), c[1][k+2]);
    int h2 = max(max(c[2][k], c[2][k+1]), c[2][k+2]);
    m[k] = max(h0, max(h1, h2));
  }

  if constexpr (R1){
    int val[8];
    #pragma unroll
    for (int k = 0; k < 8; ++k){
      int l = c[1][k+1];                 // center label (pixel col x0-1+k)
      val[k] = l ? m[k] : (P + k);       // m >= l always (window has center)
    }
    if (t == 0){
      if (y == 0) val[0] = 0;            // lut[0] = 0
      else {
        // crossing pixel q = (y-1, 2047): window rows max(y-2,0)..y, cols 2046..2047
        int rr0 = (y >= 2) ? y-2 : 0;
        int rr[3] = {rr0, y-1, y};
        int mm = 0;
        #pragma unroll
        for (int j = 0; j < 3; ++j){
          float ha = hot[rr[j]*WW + 2046], hb = hot[rr[j]*WW + 2047];
          int la = (ha > 0.3f) ? rr[j]*WW + 2047 : 0;
          int lbv = (hb > 0.3f) ? rr[j]*WW + 2048 : 0;
          mm = max(mm, max(la, lbv));
        }
        bool fgq = hot[(y-1)*WW + 2047] > 0.3f;
        val[0] = fgq ? mm : P;
      }
    }
    *(int4*)(lut + P)     = make_int4(val[0], val[1], val[2], val[3]);
    *(int4*)(lut + P + 4) = make_int4(val[4], val[5], val[6], val[7]);
    if (y == HH-1 && t == 255){
      // position NPIX, pixel (2047,2047): window rows 2046..2047, cols 2046..2047
      int mm = max(max(c[0][8], c[0][9]), max(c[1][8], c[1][9]));
      int l = c[1][9];
      lut[NPIX] = l ? mm : NPIX;
    }
  } else {
    #pragma unroll
    for (int k = 0; k < 8; ++k){
      if (t == 0 && k == 0) continue;    // crossing handled below
      int l = c[1][k+1];
      if (l != 0 && m[k] > l) atomicMax(&lut[l], m[k]);
    }
    if (t == 0 && y > 0){
      int q = P - 1;                     // pixel (y-1, 2047)
      int l = lab[q];
      if (l != 0){
        int rr0 = (y >= 2) ? y-2 : 0;
        int rr[3] = {rr0, y-1, y};
        int mm = 0;
        #pragma unroll
        for (int j = 0; j < 3; ++j)
          mm = max(mm, max(lab[rr[j]*WW + 2046], lab[rr[j]*WW + 2047]));
        if (mm > l) atomicMax(&lut[l], mm);
      }
    }
    if (y == HH-1 && t == 255){
      int mm = max(max(c[0][8], c[0][9]), max(c[1][8], c[1][9]));
      int l = c[1][9];
      if (l != 0 && mm > l) atomicMax(&lut[l], mm);
    }
  }
}

// Materialized squaring: dst[i] = src^(HOPS+1)[i]. HOPS=7 -> ^8 (3 doublings),
// HOPS=15 -> ^16 (4 doublings). Chains restart coalesced each kernel.
template<int HOPS>
__global__ void k_compress(const int* __restrict__ src, int* __restrict__ dst){
  int wb = xcd_swz(blockIdx.x, gridDim.x);
  int base = (wb*256 + threadIdx.x) * 4;
  if (base + 3 <= NPIX){
    int4 v = *(const int4*)(src + base);
    int j0 = v.x, j1 = v.y, j2 = v.z, j3 = v.w;
    for (int k = 0; k < HOPS; ++k){
      j0 = src[j0]; j1 = src[j1]; j2 = src[j2]; j3 = src[j3];
    }
    *(int4*)(dst + base) = make_int4(j0, j1, j2, j3);
  } else {
    for (int i = base; i <= NPIX; ++i){
      int j = src[i];
      for (int k = 0; k < HOPS; ++k) j = src[j];
      dst[i] = j;
    }
  }
}

// round-1 apply: lab[p] = fg(p) ? lut1c[p+1] : 0  (lab0 never materialized)
__global__ void k_apply1(const float* __restrict__ hot, const int* __restrict__ lut,
                         int* __restrict__ lab){
  int t = blockIdx.x*256 + threadIdx.x;
  if (t >= NP4) return;
  float4 h = ((const float4*)hot)[t];
  int4 A = ((const int4*)lut)[t];
  int nb = lut[4*t + 4];                 // t=NP4-1 -> lut[NPIX], valid
  int4 L;
  L.x = (h.x > 0.3f) ? A.y : 0;
  L.y = (h.y > 0.3f) ? A.z : 0;
  L.z = (h.z > 0.3f) ? A.w : 0;
  L.w = (h.w > 0.3f) ? nb  : 0;
  ((int4*)lab)[t] = L;
}

__global__ void k_apply(int* __restrict__ lab, const int* __restrict__ lut){
  int t = blockIdx.x*256 + threadIdx.x;
  if (t >= NP4) return;
  int4 L = ((int4*)lab)[t];
  L.x = lut[L.x]; L.y = lut[L.y]; L.z = lut[L.z]; L.w = lut[L.w];
  ((int4*)lab)[t] = L;
}

// ---------------- rank relabel ----------------

__global__ void k_clear(int* __restrict__ pres){
  int t = blockIdx.x*256 + threadIdx.x;
  if (t < NP4) ((int4*)pres)[t] = make_int4(0,0,0,0);
  else if (t == NP4) pres[NPIX] = 0;
}

// round-3 apply fused with presence marking
__global__ void k_apply_mark(int* __restrict__ lab, const int* __restrict__ lut, int* __restrict__ pres){
  int t = blockIdx.x*256 + threadIdx.x;
  if (t >= NP4) return;
  int4 L = ((int4*)lab)[t];
  L.x = lut[L.x]; L.y = lut[L.y]; L.z = lut[L.z]; L.w = lut[L.w];
  ((int4*)lab)[t] = L;
  pres[L.x] = 1; pres[L.y] = 1; pres[L.z] = 1; pres[L.w] = 1;
}

__global__ void k_scan1(const int* __restrict__ pres, int* __restrict__ bsum){
  __shared__ int sh[256];
  int t = threadIdx.x;
  int base = blockIdx.x*4096 + t*16;
  int run = 0;
  if (base + 15 <= NPIX){
    const int4* p4 = (const int4*)(pres + base);
    #pragma unroll
    for (int k = 0; k < 4; ++k){ int4 v = p4[k]; run += v.x + v.y + v.z + v.w; }
  } else {
    for (int k = 0; k < 16; ++k){ int idx = base + k; if (idx <= NPIX) run += pres[idx]; }
  }
  sh[t] = run; __syncthreads();
  for (int o = 128; o > 0; o >>= 1){ if (t < o) sh[t] += sh[t+o]; __syncthreads(); }
  if (t == 0) bsum[blockIdx.x] = sh[0];
}

// block-sum exclusive scan + stats clear (fused; runs before stats1)
__global__ void k_scan2(int* __restrict__ bs, int nb, float* __restrict__ st){
  __shared__ int sh[1024];
  int t = threadIdx.x;
  if (t < S_TOT) st[t] = (t >= S_KMINX) ? -0.0f : 0.0f;      // -0.0f bits == encf(0.0f)
  if (t + 1024 < S_TOT) st[t + 1024] = (t + 1024 >= S_KMINX) ? -0.0f : 0.0f;
  int v = (t < nb) ? bs[t] : 0;
  sh[t] = v; __syncthreads();
  for (int o = 1; o < 1024; o <<= 1){
    int add = (t >= o) ? sh[t-o] : 0;
    __syncthreads();
    sh[t] += add;
    __syncthreads();
  }
  if (t < nb) bs[t] = (t == 0) ? 0 : sh[t-1];   // exclusive
  if (t == 1023 && nb > 1024) bs[1024] = sh[1023]; // nb <= 1025 here
}

__global__ void k_scan3(int* __restrict__ pres, const int* __restrict__ bsum){
  __shared__ int sh[256];
  int t = threadIdx.x;
  int base = blockIdx.x*4096 + t*16;
  int v[16];
  int run = 0;
  bool vec = (base + 15 <= NPIX);
  if (vec){
    const int4* p4 = (const int4*)(pres + base);
    #pragma unroll
    for (int k = 0; k < 4; ++k){
      int4 q = p4[k];
      run += q.x; v[4*k]   = run;
      run += q.y; v[4*k+1] = run;
      run += q.z; v[4*k+2] = run;
      run += q.w; v[4*k+3] = run;
    }
  } else {
    #pragma unroll
    for (int k = 0; k < 16; ++k){
      int idx = base + k;
      int x = (idx <= NPIX) ? pres[idx] : 0;
      run += x; v[k] = run;
    }
  }
  sh[t] = run; __syncthreads();
  for (int o = 1; o < 256; o <<= 1){
    int add = (t >= o) ? sh[t-o] : 0;
    __syncthreads();
    sh[t] += add;
    __syncthreads();
  }
  int offs = bsum[blockIdx.x] + sh[t] - run - 1;   // rank = inclusive cumsum - 1
  if (vec){
    int4* p4 = (int4*)(pres + base);
    #pragma unroll
    for (int k = 0; k < 4; ++k)
      p4[k] = make_int4(v[4*k]+offs, v[4*k+1]+offs, v[4*k+2]+offs, v[4*k+3]+offs);
  } else {
    for (int k = 0; k < 16; ++k){ int idx = base + k; if (idx <= NPIX) pres[idx] = v[k] + offs; }
  }
}

// ---------------- per-segment stats ----------------

// fused: segment-id relabel (rank clamp) + first-moment accumulation
__global__ void k_stats1(int* __restrict__ lab, const int* __restrict__ ranks,
                         const float* __restrict__ hot, float* __restrict__ st){
  __shared__ float sh[256];
  float a0 = 0.f, x0 = 0.f, y0 = 0.f, h0 = 0.f;
  int stride = gridDim.x * blockDim.x;
  for (int t = blockIdx.x*blockDim.x + threadIdx.x; t < NP4; t += stride){
    int4 L = ((int4*)lab)[t];
    float4 hq = ((const float4*)hot)[t];
    int p0 = t*4;
    float xb = (float)(p0 & (WW-1));
    float yf = (float)(p0 >> 11);
    int ls[4] = {L.x, L.y, L.z, L.w};
    float hs[4] = {hq.x, hq.y, hq.z, hq.w};
    #pragma unroll
    for (int j = 0; j < 4; ++j){
      int r = ranks[ls[j]];
      int s = (r >= MAXNC) ? 0 : r;
      ls[j] = s;
      float xf = xb + (float)j;
      if (s == 0){ a0 += 1.f; x0 += xf; y0 += yf; h0 += hs[j]; }
      else {
        atomicAdd(&st[S_AREA+s], 1.f);
        atomicAdd(&st[S_SX+s], xf);
        atomicAdd(&st[S_SY+s], yf);
        atomicAdd(&st[S_SHOT+s], hs[j]);
      }
    }
    ((int4*)lab)[t] = make_int4(ls[0], ls[1], ls[2], ls[3]);
  }
  a0 = blockReduceSum(a0, sh);
  x0 = blockReduceSum(x0, sh);
  y0 = blockReduceSum(y0, sh);
  h0 = blockReduceSum(h0, sh);
  if (threadIdx.x == 0){
    atomicAdd(&st[S_AREA], a0);
    atomicAdd(&st[S_SX], x0);
    atomicAdd(&st[S_SY], y0);
    atomicAdd(&st[S_SHOT], h0);
  }
}

__global__ void k_mu(float* __restrict__ st){
  int s = threadIdx.x;
  if (s < MAXNC){
    float a = st[S_AREA+s];
    st[S_MUX+s] = st[S_SX+s] / a;   // 0/0 -> NaN matches ref
    st[S_MUY+s] = st[S_SY+s] / a;
  }
}

__global__ void k_stats2(const int* __restrict__ lab, float* __restrict__ st){
  __shared__ float sh[256];
  float xx0 = 0.f, xy0 = 0.f, yy0 = 0.f;
  int stride = gridDim.x * blockDim.x;
  for (int t = blockIdx.x*blockDim.x + threadIdx.x; t < NP4; t += stride){
    int4 L = ((int4*)lab)[t];
    int p0 = t*4;
    float xb = (float)(p0 & (WW-1));
    float yf = (float)(p0 >> 11);
    int ls[4] = {L.x, L.y, L.z, L.w};
    #pragma unroll
    for (int j = 0; j < 4; ++j){
      int s = ls[j];
      float cx = xb + (float)j - st[S_MUX+s];
      float cy = yf - st[S_MUY+s];
      float pxx = cx*cx, pxy = cx*cy, pyy = cy*cy;
      if (s == 0){ xx0 += pxx; xy0 += pxy; yy0 += pyy; }
      else {
        atomicAdd(&st[S_CXX+s], pxx);
        atomicAdd(&st[S_CXY+s], pxy);
        atomicAdd(&st[S_CYY+s], pyy);
      }
    }
  }
  xx0 = blockReduceSum(xx0, sh);
  xy0 = blockReduceSum(xy0, sh);
  yy0 = blockReduceSum(yy0, sh);
  if (threadIdx.x == 0){
    atomicAdd(&st[S_CXX], xx0);
    atomicAdd(&st[S_CXY], xy0);
    atomicAdd(&st[S_CYY], yy0);
  }
}

__global__ void k_svd(float* __restrict__ st){
  int s = threadIdx.x;
  if (s >= MAXNC) return;
  float a = st[S_AREA+s];
  float vx  = st[S_CXX+s] / a;
  float vxy = st[S_CXY+s] / a;
  float vy  = st[S_CYY+s] / a;
  float theta = 0.5f * atan2f(2.0f*vxy, vx - vy);
  float c = cosf(theta), sn = sinf(theta);
  float tr = vx + vy;
  float d = (vx - vy)*(vx - vy) + 4.0f*vxy*vxy;
  float disc = fmaxf(d, 1e-12f);
  float sq = sqrtf(disc);
  float l2 = fmaxf((tr - sq)*0.5f, 0.0f);
  float margin = sqrtf(sqrtf(l2)) * 4.0f;   // sqrt(l[:,1]) * 4 * MAR, l = sqrt(eig)
  st[S_RC+s] = c;
  st[S_RS+s] = sn;
  st[S_MG+s] = margin;
}

__global__ void k_stats3(const int* __restrict__ lab, float* __restrict__ st){
  __shared__ float sh[256];
  unsigned int* ku = (unsigned int*)st;
  float mnx =  INFINITY, mxx = -INFINITY, mny =  INFINITY, mxy = -INFINITY;
  int stride = gridDim.x * blockDim.x;
  for (int t = blockIdx.x*blockDim.x + threadIdx.x; t < NP4; t += stride){
    int4 L = ((int4*)lab)[t];
    int p0 = t*4;
    float xb = (float)(p0 & (WW-1));
    float yf = (float)(p0 >> 11);
    int ls[4] = {L.x, L.y, L.z, L.w};
    #pragma unroll
    for (int j = 0; j < 4; ++j){
      int s = ls[j];
      float cx = xb + (float)j - st[S_MUX+s];
      float cy = yf - st[S_MUY+s];
      float c = st[S_RC+s], sn = st[S_RS+s];
      float rx =  c*cx + sn*cy;   // m^T @ coords
      float ry = -sn*cx + c*cy;
      if (s == 0){
        mnx = fminf(mnx, rx); mxx = fmaxf(mxx, rx);
        mny = fminf(mny, ry); mxy = fmaxf(mxy, ry);
      } else {
        atomicMin(&ku[S_KMINX+s], encf(rx));
        atomicMax(&ku[S_KMAXX+s], encf(rx));
        atomicMin(&ku[S_KMINY+s], encf(ry));
        atomicMax(&ku[S_KMAXY+s], encf(ry));
      }
    }
  }
  mnx = blockReduceMin(mnx, sh);
  mxx = blockReduceMax(mxx, sh);
  mny = blockReduceMin(mny, sh);
  mxy = blockReduceMax(mxy, sh);
  if (threadIdx.x == 0){
    atomicMin(&ku[S_KMINX], encf(mnx));
    atomicMax(&ku[S_KMAXX], encf(mxx));
    atomicMin(&ku[S_KMINY], encf(mny));
    atomicMax(&ku[S_KMAXY], encf(mxy));
  }
}

__global__ void k_final(const float* __restrict__ st, const float* __restrict__ scale, float* __restrict__ out){
  int s = threadIdx.x;
  if (s >= MAXNC) return;
  const unsigned int* ku = (const unsigned int*)st;
  float a   = st[S_AREA+s];
  float lvl = st[S_SHOT+s];
  float mg  = st[S_MG+s];
  float minx = decf(ku[S_KMINX+s]) - mg;   // key init enc(0) == clamp vs 0
  float maxx = decf(ku[S_KMAXX+s]) + mg;
  float miny = decf(ku[S_KMINY+s]) - mg;
  float maxy = decf(ku[S_KMAXY+s]) + mg;
  bool ok = (lvl/a > 0.7f) && (maxx - minx > 5.0f) && (maxy - miny > 5.0f);  // NaN -> false
  float c = st[S_RC+s], sn = st[S_RS+s];
  float mux = st[S_MUX+s], muy = st[S_MUY+s];
  float sc2 = scale[0] * 2.0f;
  float rxs[5] = {minx, maxx, maxx, minx, minx};
  float rys[5] = {miny, miny, maxy, maxy, miny};
  #pragma unroll
  for (int k = 0; k < 5; ++k){
    float X = c*rxs[k] - sn*rys[k] + mux;   // m @ rec + mu
    float Y = sn*rxs[k] + c*rys[k] + muy;
    out[s*10 + 2*k + 0] = ok ? X * sc2 : 0.0f;
    out[s*10 + 2*k + 1] = ok ? Y * sc2 : 0.0f;
  }
}

// ---------------- host ----------------

extern "C" void kernel_launch(void* const* d_in, const int* in_sizes, int n_in,
                              void* d_out, int out_size, void* d_ws, size_t ws_size,
                              hipStream_t stream) {
  const float* hot   = (const float*)d_in[0];
  const float* scale = (const float*)d_in[1];
  float* out = (float*)d_out;

  char* ws = (char*)d_ws;
  size_t off = 0;
  int* lab  = (int*)(ws + off); off += (size_t)NPIX * 4;
  int* lutA = (int*)(ws + off); off += (size_t)(NPIX + 64) * 4;
  int* lutB = (int*)(ws + off); off += (size_t)(NPIX + 64) * 4;
  int* bsum = (int*)(ws + off); off += 2048 * 4;
  float* st = (float*)(ws + off); off += S_TOT * 4;

  dim3 B(256);
  int g4  = (NP4 + 255) / 256;          // 4096  — NP4-range kernels
  int g4t = (NP4 + 256) / 256;          // 4097  — NP4+1 threads (tail element)

  int* cur = lutA;
  int* alt = lutB;

  // round 1: dense scatter from hot (writes lut fully; no init needed),
  // then lut^4096 = ((^16)^16)^16, then lab = lut[p+1]*fg
  k_scatter_row<true ><<<HH, B, 0, stream>>>(hot, lab, cur);
  for (int i = 0; i < 3; ++i){
    k_compress<15><<<g4t, B, 0, stream>>>(cur, alt);
    int* tp = cur; cur = alt; alt = tp;
  }
  k_apply1<<<g4, B, 0, stream>>>(hot, cur, lab);

  // round 2: scatter + ^64 via two materialized ^8 passes
  k_scatter_row<false><<<HH, B, 0, stream>>>(hot, lab, cur);
  for (int i = 0; i < 2; ++i){
    k_compress<7><<<g4t, B, 0, stream>>>(cur, alt);
    int* tp = cur; cur = alt; alt = tp;
  }
  k_apply<<<g4, B, 0, stream>>>(lab, cur);

  // round 3: scatter + ^8
  k_scatter_row<false><<<HH, B, 0, stream>>>(hot, lab, cur);
  k_compress<7><<<g4t, B, 0, stream>>>(cur, alt);
  { int* tp = cur; cur = alt; alt = tp; }

  // rank relabel: round-3 apply fused with presence marking
  int* pres = alt;                      // non-current lut buffer is free now
  k_clear<<<g4t, B, 0, stream>>>(pres);
  k_apply_mark<<<g4, B, 0, stream>>>(lab, cur, pres);
  int NB = (NPIX + 1 + 4095) / 4096;    // 1025
  k_scan1<<<NB, B, 0, stream>>>(pres, bsum);
  k_scan2<<<1, 1024, 0, stream>>>(bsum, NB, st);   // + stats clear
  k_scan3<<<NB, B, 0, stream>>>(pres, bsum);

  // per-segment stats (seg relabel fused into stats1)
  k_stats1<<<2048, B, 0, stream>>>(lab, pres, hot, st);
  k_mu<<<1, 128, 0, stream>>>(st);
  k_stats2<<<2048, B, 0, stream>>>(lab, st);
  k_svd<<<1, 128, 0, stream>>>(st);
  k_stats3<<<2048, B, 0, stream>>>(lab, st);
  k_final<<<1, 128, 0, stream>>>(st, scale, out);
}

// Round 6
// 403.675 us; speedup vs baseline: 1.5708x; 1.3704x over previous
//
#include <hip/hip_runtime.h>
#include <math.h>

#define HH 2048
#define WW 2048
#define NPIX (HH*WW)
#define NP4  (NPIX/4)
#define MAXNC 100

// stats layout (floats; key regions reinterpreted as uint32)
#define S_AREA 0
#define S_SX   100
#define S_SY   200
#define S_SHOT 300
#define S_MUX  400
#define S_MUY  500
#define S_CXX  600
#define S_CXY  700
#define S_CYY  800
#define S_RC   900
#define S_RS   1000
#define S_MG   1100
#define S_KMINX 1200
#define S_KMAXX 1300
#define S_KMINY 1400
#define S_KMAXY 1500
#define S_TOT  1600

__device__ __forceinline__ unsigned int encf(float f){
  unsigned int u = __float_as_uint(f);
  return (u & 0x80000000u) ? ~u : (u | 0x80000000u);
}
__device__ __forceinline__ float decf(unsigned int k){
  return (k & 0x80000000u) ? __uint_as_float(k & 0x7fffffffu) : __uint_as_float(~k);
}

// bijective XCD swizzle: round-robin block->XCD dispatch becomes a contiguous
// work range per XCD so its private L2 holds one slab.
__device__ __forceinline__ int xcd_swz(int b, int nwg){
  int q = nwg >> 3, r = nwg & 7;
  int xcd = b & 7, o = b >> 3;
  return (xcd < r ? xcd*(q+1) : r*(q+1) + (xcd-r)*q) + o;
}

__device__ __forceinline__ float blockReduceSum(float v, float* sh){
  int t = threadIdx.x;
  __syncthreads();
  sh[t] = v; __syncthreads();
  for (int o = 128; o > 0; o >>= 1){ if (t < o) sh[t] += sh[t+o]; __syncthreads(); }
  float r = sh[0]; __syncthreads();
  return r;
}
__device__ __forceinline__ float blockReduceMin(float v, float* sh){
  int t = threadIdx.x;
  __syncthreads();
  sh[t] = v; __syncthreads();
  for (int o = 128; o > 0; o >>= 1){ if (t < o) sh[t] = fminf(sh[t], sh[t+o]); __syncthreads(); }
  float r = sh[0]; __syncthreads();
  return r;
}
__device__ __forceinline__ float blockReduceMax(float v, float* sh){
  int t = threadIdx.x;
  __syncthreads();
  sh[t] = v; __syncthreads();
  for (int o = 128; o > 0; o >>= 1){ if (t < o) sh[t] = fmaxf(sh[t], sh[t+o]); __syncthreads(); }
  float r = sh[0]; __syncthreads();
  return r;
}

// ---------------- CCL ----------------

// 3x3-max scatter, one block per lut-position row (y), 8 positions/thread.
// R1: labels computed from hot in-register; lut written DENSELY.
template<bool R1>
__global__ __launch_bounds__(256) void k_scatter_row(const float* __restrict__ hot,
                                                     const int* __restrict__ lab,
                                                     int* __restrict__ lut){
  int y  = xcd_swz(blockIdx.x, HH);
  int t  = threadIdx.x;
  int x0 = t << 3;                       // first normal pixel col (pixels x0-1..x0+6)
  int P  = (y << 11) + x0;               // first lut position
  int ci = t << 1;                       // aligned int4 col of x0
  int cim = (ci > 0) ? ci - 1 : 0;
  int rows3[3];
  rows3[0] = (y > 0) ? y-1 : 0;
  rows3[1] = y;
  rows3[2] = (y < HH-1) ? y+1 : HH-1;

  int c[3][10];                          // cols x0-2 .. x0+7 per row
  #pragma unroll
  for (int j = 0; j < 3; ++j){
    int rb = rows3[j] << 9;              // int4-row base
    if constexpr (R1){
      const float4* h4 = (const float4*)hot;
      float4 a = h4[rb + cim], b = h4[rb + ci], d = h4[rb + ci + 1];
      int lb = rows3[j]*WW + (x0 - 2) + 1;    // label of col x0-2
      c[j][0] = (a.z > 0.3f) ? lb   : 0;
      c[j][1] = (a.w > 0.3f) ? lb+1 : 0;
      c[j][2] = (b.x > 0.3f) ? lb+2 : 0;
      c[j][3] = (b.y > 0.3f) ? lb+3 : 0;
      c[j][4] = (b.z > 0.3f) ? lb+4 : 0;
      c[j][5] = (b.w > 0.3f) ? lb+5 : 0;
      c[j][6] = (d.x > 0.3f) ? lb+6 : 0;
      c[j][7] = (d.y > 0.3f) ? lb+7 : 0;
      c[j][8] = (d.z > 0.3f) ? lb+8 : 0;
      c[j][9] = (d.w > 0.3f) ? lb+9 : 0;
    } else {
      const int4* l4 = (const int4*)lab;
      int4 a = l4[rb + cim], b = l4[rb + ci], d = l4[rb + ci + 1];
      c[j][0] = a.z; c[j][1] = a.w;
      c[j][2] = b.x; c[j][3] = b.y; c[j][4] = b.z; c[j][5] = b.w;
      c[j][6] = d.x; c[j][7] = d.y; c[j][8] = d.z; c[j][9] = d.w;
    }
    if (t == 0){ c[j][0] = c[j][2]; c[j][1] = c[j][2]; }  // clamp cols -2,-1 -> col 0
  }

  int m[8];
  #pragma unroll
  for (int k = 0; k < 8; ++k){
    int h0 = max(max(c[0][k], c[0][k+1]), c[0][k+2]);
    int h1 = max(max(c[1][k], c[1][k+1]), c[1][k+2]);
    int h2 = max(max(c[2][k], c[2][k+1]), c[2][k+2]);
    m[k] = max(h0, max(h1, h2));
  }

  if constexpr (R1){
    int val[8];
    #pragma unroll
    for (int k = 0; k < 8; ++k){
      int l = c[1][k+1];                 // center label (pixel col x0-1+k)
      val[k] = l ? m[k] : (P + k);       // m >= l always (window has center)
    }
    if (t == 0){
      if (y == 0) val[0] = 0;            // lut[0] = 0
      else {
        // crossing pixel q = (y-1, 2047): window rows max(y-2,0)..y, cols 2046..2047
        int rr0 = (y >= 2) ? y-2 : 0;
        int rr[3] = {rr0, y-1, y};
        int mm = 0;
        #pragma unroll
        for (int j = 0; j < 3; ++j){
          float ha = hot[rr[j]*WW + 2046], hb = hot[rr[j]*WW + 2047];
          int la = (ha > 0.3f) ? rr[j]*WW + 2047 : 0;
          int lbv = (hb > 0.3f) ? rr[j]*WW + 2048 : 0;
          mm = max(mm, max(la, lbv));
        }
        bool fgq = hot[(y-1)*WW + 2047] > 0.3f;
        val[0] = fgq ? mm : P;
      }
    }
    *(int4*)(lut + P)     = make_int4(val[0], val[1], val[2], val[3]);
    *(int4*)(lut + P + 4) = make_int4(val[4], val[5], val[6], val[7]);
    if (y == HH-1 && t == 255){
      // position NPIX, pixel (2047,2047): window rows 2046..2047, cols 2046..2047
      int mm = max(max(c[0][8], c[0][9]), max(c[1][8], c[1][9]));
      int l = c[1][9];
      lut[NPIX] = l ? mm : NPIX;
    }
  } else {
    #pragma unroll
    for (int k = 0; k < 8; ++k){
      if (t == 0 && k == 0) continue;    // crossing handled below
      int l = c[1][k+1];
      if (l != 0 && m[k] > l) atomicMax(&lut[l], m[k]);
    }
    if (t == 0 && y > 0){
      int q = P - 1;                     // pixel (y-1, 2047)
      int l = lab[q];
      if (l != 0){
        int rr0 = (y >= 2) ? y-2 : 0;
        int rr[3] = {rr0, y-1, y};
        int mm = 0;
        #pragma unroll
        for (int j = 0; j < 3; ++j)
          mm = max(mm, max(lab[rr[j]*WW + 2046], lab[rr[j]*WW + 2047]));
        if (mm > l) atomicMax(&lut[l], mm);
      }
    }
    if (y == HH-1 && t == 255){
      int mm = max(max(c[0][8], c[0][9]), max(c[1][8], c[1][9]));
      int l = c[1][9];
      if (l != 0 && mm > l) atomicMax(&lut[l], mm);
    }
  }
}

// Materialized composition: dst[i] = src^(HOPS+1)[i], with early exit at
// fixed points (exact: fixed points absorb further applications).
template<int HOPS>
__global__ void k_compress(const int* __restrict__ src, int* __restrict__ dst){
  int wb = xcd_swz(blockIdx.x, gridDim.x);
  int base = (wb*256 + threadIdx.x) * 4;
  if (base + 3 <= NPIX){
    int4 v = *(const int4*)(src + base);
    int j0 = v.x, j1 = v.y, j2 = v.z, j3 = v.w;
    #pragma unroll 1
    for (int k = 0; k < HOPS; ++k){
      int n0 = src[j0], n1 = src[j1], n2 = src[j2], n3 = src[j3];
      bool done = (n0==j0) && (n1==j1) && (n2==j2) && (n3==j3);
      j0 = n0; j1 = n1; j2 = n2; j3 = n3;
      if (done) break;
    }
    *(int4*)(dst + base) = make_int4(j0, j1, j2, j3);
  } else {
    for (int i = base; i <= NPIX; ++i){
      int j = src[i];
      for (int k = 0; k < HOPS; ++k){
        int n = src[j];
        if (n == j) break;
        j = n;
      }
      dst[i] = j;
    }
  }
}

// round-1 apply: lab[p] = fg(p) ? lut[p+1] : 0
__global__ void k_apply1(const float* __restrict__ hot, const int* __restrict__ lut,
                         int* __restrict__ lab){
  int t = blockIdx.x*256 + threadIdx.x;
  if (t >= NP4) return;
  float4 h = ((const float4*)hot)[t];
  int4 A = ((const int4*)lut)[t];
  int nb = lut[4*t + 4];                 // t=NP4-1 -> lut[NPIX], valid
  int4 L;
  L.x = (h.x > 0.3f) ? A.y : 0;
  L.y = (h.y > 0.3f) ? A.z : 0;
  L.z = (h.z > 0.3f) ? A.w : 0;
  L.w = (h.w > 0.3f) ? nb  : 0;
  ((int4*)lab)[t] = L;
}

__global__ void k_apply(int* __restrict__ lab, const int* __restrict__ lut){
  int t = blockIdx.x*256 + threadIdx.x;
  if (t >= NP4) return;
  int4 L = ((int4*)lab)[t];
  L.x = lut[L.x]; L.y = lut[L.y]; L.z = lut[L.z]; L.w = lut[L.w];
  ((int4*)lab)[t] = L;
}

// round-3: lab = lut^8[lab] fused as a capped in-register chase (the lut array
// is dead afterwards, so no materialization needed) + presence marking.
__global__ void k_chase_mark(int* __restrict__ lab, const int* __restrict__ lut,
                             unsigned char* __restrict__ presb){
  int t = blockIdx.x*256 + threadIdx.x;
  if (t >= NP4) return;
  int4 L = ((int4*)lab)[t];
  int j0 = L.x, j1 = L.y, j2 = L.z, j3 = L.w;
  #pragma unroll 1
  for (int k = 0; k < 8; ++k){
    int n0 = lut[j0], n1 = lut[j1], n2 = lut[j2], n3 = lut[j3];
    bool done = (n0==j0) && (n1==j1) && (n2==j2) && (n3==j3);
    j0 = n0; j1 = n1; j2 = n2; j3 = n3;
    if (done) break;
  }
  ((int4*)lab)[t] = make_int4(j0, j1, j2, j3);
  presb[j0] = 1; presb[j1] = 1; presb[j2] = 1; presb[j3] = 1;
}

// ---------------- rank relabel (byte presence array) ----------------

__global__ void k_clearb(unsigned char* __restrict__ presb){
  int base = (blockIdx.x*256 + threadIdx.x) * 16;
  if (base + 15 <= NPIX) *(int4*)(presb + base) = make_int4(0,0,0,0);
  else { for (int k = 0; k < 16; ++k){ int idx = base + k; if (idx <= NPIX) presb[idx] = 0; } }
}

__global__ void k_scan1(const unsigned char* __restrict__ presb, int* __restrict__ bsum){
  __shared__ int sh[256];
  int t = threadIdx.x;
  int base = blockIdx.x*4096 + t*16;
  int run = 0;
  if (base + 15 <= NPIX){
    int4 v = *(const int4*)(presb + base);
    run = (int)((((unsigned)v.x & 0x01010101u) * 0x01010101u) >> 24)
        + (int)((((unsigned)v.y & 0x01010101u) * 0x01010101u) >> 24)
        + (int)((((unsigned)v.z & 0x01010101u) * 0x01010101u) >> 24)
        + (int)((((unsigned)v.w & 0x01010101u) * 0x01010101u) >> 24);
  } else {
    for (int k = 0; k < 16; ++k){ int idx = base + k; if (idx <= NPIX) run += presb[idx]; }
  }
  sh[t] = run; __syncthreads();
  for (int o = 128; o > 0; o >>= 1){ if (t < o) sh[t] += sh[t+o]; __syncthreads(); }
  if (t == 0) bsum[blockIdx.x] = sh[0];
}

// block-sum exclusive scan + stats clear (fused)
__global__ void k_scan2(int* __restrict__ bs, int nb, float* __restrict__ st){
  __shared__ int sh[1024];
  int t = threadIdx.x;
  if (t < S_TOT) st[t] = (t >= S_KMINX) ? -0.0f : 0.0f;      // -0.0f bits == encf(0.0f)
  if (t + 1024 < S_TOT) st[t + 1024] = (t + 1024 >= S_KMINX) ? -0.0f : 0.0f;
  int v = (t < nb) ? bs[t] : 0;
  sh[t] = v; __syncthreads();
  for (int o = 1; o < 1024; o <<= 1){
    int add = (t >= o) ? sh[t-o] : 0;
    __syncthreads();
    sh[t] += add;
    __syncthreads();
  }
  if (t < nb) bs[t] = (t == 0) ? 0 : sh[t-1];   // exclusive
  if (t == 1023 && nb > 1024) bs[1024] = sh[1023]; // nb <= 1025 here
}

__global__ void k_scan3(const unsigned char* __restrict__ presb,
                        const int* __restrict__ bsum, int* __restrict__ ranks){
  __shared__ int sh[256];
  int t = threadIdx.x;
  int base = blockIdx.x*4096 + t*16;
  int v[16];
  int run = 0;
  bool vec = (base + 15 <= NPIX);
  if (vec){
    int4 q = *(const int4*)(presb + base);
    unsigned w[4] = {(unsigned)q.x, (unsigned)q.y, (unsigned)q.z, (unsigned)q.w};
    #pragma unroll
    for (int a = 0; a < 4; ++a){
      #pragma unroll
      for (int b = 0; b < 4; ++b){ run += (w[a] >> (8*b)) & 1; v[a*4+b] = run; }
    }
  } else {
    for (int k = 0; k < 16; ++k){
      int idx = base + k;
      int x = (idx <= NPIX) ? presb[idx] : 0;
      run += x; v[k] = run;
    }
  }
  sh[t] = run; __syncthreads();
  for (int o = 1; o < 256; o <<= 1){
    int add = (t >= o) ? sh[t-o] : 0;
    __syncthreads();
    sh[t] += add;
    __syncthreads();
  }
  int offs = bsum[blockIdx.x] + sh[t] - run - 1;   // rank = inclusive cumsum - 1
  if (vec){
    int4* r4 = (int4*)(ranks + base);
    #pragma unroll
    for (int k = 0; k < 4; ++k)
      r4[k] = make_int4(v[4*k]+offs, v[4*k+1]+offs, v[4*k+2]+offs, v[4*k+3]+offs);
  } else {
    for (int k = 0; k < 16; ++k){ int idx = base + k; if (idx <= NPIX) ranks[idx] = v[k] + offs; }
  }
}

// ---------------- per-segment stats ----------------

// fused: segment-id relabel (rank clamp) + first-moment accumulation
__global__ void k_stats1(int* __restrict__ lab, const int* __restrict__ ranks,
                         const float* __restrict__ hot, float* __restrict__ st){
  __shared__ float sh[256];
  float a0 = 0.f, x0 = 0.f, y0 = 0.f, h0 = 0.f;
  int stride = gridDim.x * blockDim.x;
  for (int t = blockIdx.x*blockDim.x + threadIdx.x; t < NP4; t += stride){
    int4 L = ((int4*)lab)[t];
    float4 hq = ((const float4*)hot)[t];
    int p0 = t*4;
    float xb = (float)(p0 & (WW-1));
    float yf = (float)(p0 >> 11);
    int ls[4] = {L.x, L.y, L.z, L.w};
    float hs[4] = {hq.x, hq.y, hq.z, hq.w};
    #pragma unroll
    for (int j = 0; j < 4; ++j){
      int r = ranks[ls[j]];
      int s = (r >= MAXNC) ? 0 : r;
      ls[j] = s;
      float xf = xb + (float)j;
      if (s == 0){ a0 += 1.f; x0 += xf; y0 += yf; h0 += hs[j]; }
      else {
        atomicAdd(&st[S_AREA+s], 1.f);
        atomicAdd(&st[S_SX+s], xf);
        atomicAdd(&st[S_SY+s], yf);
        atomicAdd(&st[S_SHOT+s], hs[j]);
      }
    }
    ((int4*)lab)[t] = make_int4(ls[0], ls[1], ls[2], ls[3]);
  }
  a0 = blockReduceSum(a0, sh);
  x0 = blockReduceSum(x0, sh);
  y0 = blockReduceSum(y0, sh);
  h0 = blockReduceSum(h0, sh);
  if (threadIdx.x == 0){
    atomicAdd(&st[S_AREA], a0);
    atomicAdd(&st[S_SX], x0);
    atomicAdd(&st[S_SY], y0);
    atomicAdd(&st[S_SHOT], h0);
  }
}

__global__ void k_mu(float* __restrict__ st){
  int s = threadIdx.x;
  if (s < MAXNC){
    float a = st[S_AREA+s];
    st[S_MUX+s] = st[S_SX+s] / a;   // 0/0 -> NaN matches ref
    st[S_MUY+s] = st[S_SY+s] / a;
  }
}

__global__ void k_stats2(const int* __restrict__ lab, float* __restrict__ st){
  __shared__ float sh[256];
  float xx0 = 0.f, xy0 = 0.f, yy0 = 0.f;
  int stride = gridDim.x * blockDim.x;
  for (int t = blockIdx.x*blockDim.x + threadIdx.x; t < NP4; t += stride){
    int4 L = ((int4*)lab)[t];
    int p0 = t*4;
    float xb = (float)(p0 & (WW-1));
    float yf = (float)(p0 >> 11);
    int ls[4] = {L.x, L.y, L.z, L.w};
    #pragma unroll
    for (int j = 0; j < 4; ++j){
      int s = ls[j];
      float cx = xb + (float)j - st[S_MUX+s];
      float cy = yf - st[S_MUY+s];
      float pxx = cx*cx, pxy = cx*cy, pyy = cy*cy;
      if (s == 0){ xx0 += pxx; xy0 += pxy; yy0 += pyy; }
      else {
        atomicAdd(&st[S_CXX+s], pxx);
        atomicAdd(&st[S_CXY+s], pxy);
        atomicAdd(&st[S_CYY+s], pyy);
      }
    }
  }
  xx0 = blockReduceSum(xx0, sh);
  xy0 = blockReduceSum(xy0, sh);
  yy0 = blockReduceSum(yy0, sh);
  if (threadIdx.x == 0){
    atomicAdd(&st[S_CXX], xx0);
    atomicAdd(&st[S_CXY], xy0);
    atomicAdd(&st[S_CYY], yy0);
  }
}

__global__ void k_svd(float* __restrict__ st){
  int s = threadIdx.x;
  if (s >= MAXNC) return;
  float a = st[S_AREA+s];
  float vx  = st[S_CXX+s] / a;
  float vxy = st[S_CXY+s] / a;
  float vy  = st[S_CYY+s] / a;
  float theta = 0.5f * atan2f(2.0f*vxy, vx - vy);
  float c = cosf(theta), sn = sinf(theta);
  float tr = vx + vy;
  float d = (vx - vy)*(vx - vy) + 4.0f*vxy*vxy;
  float disc = fmaxf(d, 1e-12f);
  float sq = sqrtf(disc);
  float l2 = fmaxf((tr - sq)*0.5f, 0.0f);
  float margin = sqrtf(sqrtf(l2)) * 4.0f;   // sqrt(l[:,1]) * 4 * MAR, l = sqrt(eig)
  st[S_RC+s] = c;
  st[S_RS+s] = sn;
  st[S_MG+s] = margin;
}

__global__ void k_stats3(const int* __restrict__ lab, float* __restrict__ st){
  __shared__ float sh[256];
  unsigned int* ku = (unsigned int*)st;
  float mnx =  INFINITY, mxx = -INFINITY, mny =  INFINITY, mxy = -INFINITY;
  int stride = gridDim.x * blockDim.x;
  for (int t = blockIdx.x*blockDim.x + threadIdx.x; t < NP4; t += stride){
    int4 L = ((int4*)lab)[t];
    int p0 = t*4;
    float xb = (float)(p0 & (WW-1));
    float yf = (float)(p0 >> 11);
    int ls[4] = {L.x, L.y, L.z, L.w};
    #pragma unroll
    for (int j = 0; j < 4; ++j){
      int s = ls[j];
      float cx = xb + (float)j - st[S_MUX+s];
      float cy = yf - st[S_MUY+s];
      float c = st[S_RC+s], sn = st[S_RS+s];
      float rx =  c*cx + sn*cy;   // m^T @ coords
      float ry = -sn*cx + c*cy;
      if (s == 0){
        mnx = fminf(mnx, rx); mxx = fmaxf(mxx, rx);
        mny = fminf(mny, ry); mxy = fmaxf(mxy, ry);
      } else {
        atomicMin(&ku[S_KMINX+s], encf(rx));
        atomicMax(&ku[S_KMAXX+s], encf(rx));
        atomicMin(&ku[S_KMINY+s], encf(ry));
        atomicMax(&ku[S_KMAXY+s], encf(ry));
      }
    }
  }
  mnx = blockReduceMin(mnx, sh);
  mxx = blockReduceMax(mxx, sh);
  mny = blockReduceMin(mny, sh);
  mxy = blockReduceMax(mxy, sh);
  if (threadIdx.x == 0){
    atomicMin(&ku[S_KMINX], encf(mnx));
    atomicMax(&ku[S_KMAXX], encf(mxx));
    atomicMin(&ku[S_KMINY], encf(mny));
    atomicMax(&ku[S_KMAXY], encf(mxy));
  }
}

__global__ void k_final(const float* __restrict__ st, const float* __restrict__ scale, float* __restrict__ out){
  int s = threadIdx.x;
  if (s >= MAXNC) return;
  const unsigned int* ku = (const unsigned int*)st;
  float a   = st[S_AREA+s];
  float lvl = st[S_SHOT+s];
  float mg  = st[S_MG+s];
  float minx = decf(ku[S_KMINX+s]) - mg;   // key init enc(0) == clamp vs 0
  float maxx = decf(ku[S_KMAXX+s]) + mg;
  float miny = decf(ku[S_KMINY+s]) - mg;
  float maxy = decf(ku[S_KMAXY+s]) + mg;
  bool ok = (lvl/a > 0.7f) && (maxx - minx > 5.0f) && (maxy - miny > 5.0f);  // NaN -> false
  float c = st[S_RC+s], sn = st[S_RS+s];
  float mux = st[S_MUX+s], muy = st[S_MUY+s];
  float sc2 = scale[0] * 2.0f;
  float rxs[5] = {minx, maxx, maxx, minx, minx};
  float rys[5] = {miny, miny, maxy, maxy, miny};
  #pragma unroll
  for (int k = 0; k < 5; ++k){
    float X = c*rxs[k] - sn*rys[k] + mux;   // m @ rec + mu
    float Y = sn*rxs[k] + c*rys[k] + muy;
    out[s*10 + 2*k + 0] = ok ? X * sc2 : 0.0f;
    out[s*10 + 2*k + 1] = ok ? Y * sc2 : 0.0f;
  }
}

// ---------------- host ----------------

extern "C" void kernel_launch(void* const* d_in, const int* in_sizes, int n_in,
                              void* d_out, int out_size, void* d_ws, size_t ws_size,
                              hipStream_t stream) {
  const float* hot   = (const float*)d_in[0];
  const float* scale = (const float*)d_in[1];
  float* out = (float*)d_out;

  char* ws = (char*)d_ws;
  size_t off = 0;
  int* lab  = (int*)(ws + off); off += (size_t)NPIX * 4;
  int* lutA = (int*)(ws + off); off += (size_t)(NPIX + 64) * 4;
  int* lutB = (int*)(ws + off); off += (size_t)(NPIX + 64) * 4;
  int* bsum = (int*)(ws + off); off += 2048 * 4;
  float* st = (float*)(ws + off); off += S_TOT * 4;

  dim3 B(256);
  int g4  = (NP4 + 255) / 256;          // 4096  — NP4-range kernels
  int g4t = (NP4 + 256) / 256;          // 4097  — NP4+1 threads (tail element)
  int NB  = (NPIX + 1 + 4095) / 4096;   // 1025  — scan/clear blocks

  int* cur = lutA;
  int* alt = lutB;

  // round 1: dense scatter from hot, then lut^4096 = (^4)^6 exact
  k_scatter_row<true ><<<HH, B, 0, stream>>>(hot, lab, cur);
  for (int i = 0; i < 6; ++i){
    k_compress<3><<<g4t, B, 0, stream>>>(cur, alt);
    int* tp = cur; cur = alt; alt = tp;
  }                                      // cur = lutA
  k_apply1<<<g4, B, 0, stream>>>(hot, cur, lab);

  // round 2: scatter (carried lut) + ^64 = (^4)^3 exact, materialized
  k_scatter_row<false><<<HH, B, 0, stream>>>(hot, lab, cur);
  for (int i = 0; i < 3; ++i){
    k_compress<3><<<g4t, B, 0, stream>>>(cur, alt);
    int* tp = cur; cur = alt; alt = tp;
  }                                      // cur = lutB; lutA dead
  unsigned char* presb = (unsigned char*)alt;   // alt == lutA (dead) -> presence bytes
  k_clearb<<<NB, B, 0, stream>>>(presb);
  k_apply<<<g4, B, 0, stream>>>(lab, cur);

  // round 3: scatter + fused ^8 chase-apply + presence marking
  k_scatter_row<false><<<HH, B, 0, stream>>>(hot, lab, cur);
  k_chase_mark<<<g4, B, 0, stream>>>(lab, cur, presb);

  // rank relabel over byte presence; ranks reuse the dead lut (cur)
  int* ranks = cur;
  k_scan1<<<NB, B, 0, stream>>>(presb, bsum);
  k_scan2<<<1, 1024, 0, stream>>>(bsum, NB, st);   // + stats clear
  k_scan3<<<NB, B, 0, stream>>>(presb, bsum, ranks);

  // per-segment stats (seg relabel fused into stats1)
  k_stats1<<<2048, B, 0, stream>>>(lab, ranks, hot, st);
  k_mu<<<1, 128, 0, stream>>>(st);
  k_stats2<<<2048, B, 0, stream>>>(lab, st);
  k_svd<<<1, 128, 0, stream>>>(st);
  k_stats3<<<2048, B, 0, stream>>>(lab, st);
  k_final<<<1, 128, 0, stream>>>(st, scale, out);
}

// Round 7
// 401.456 us; speedup vs baseline: 1.5794x; 1.0055x over previous
//
#include <hip/hip_runtime.h>
#include <math.h>

#define HH 2048
#define WW 2048
#define NPIX (HH*WW)
#define NP4  (NPIX/4)
#define MAXNC 100

// stats layout (floats; key regions reinterpreted as uint32)
#define S_AREA 0
#define S_SX   100
#define S_SY   200
#define S_SHOT 300
#define S_MUX  400
#define S_MUY  500
#define S_CXX  600
#define S_CXY  700
#define S_CYY  800
#define S_RC   900
#define S_RS   1000
#define S_MG   1100
#define S_KMINX 1200
#define S_KMAXX 1300
#define S_KMINY 1400
#define S_KMAXY 1500
#define S_TOT  1600

__device__ __forceinline__ unsigned int encf(float f){
  unsigned int u = __float_as_uint(f);
  return (u & 0x80000000u) ? ~u : (u | 0x80000000u);
}
__device__ __forceinline__ float decf(unsigned int k){
  return (k & 0x80000000u) ? __uint_as_float(k & 0x7fffffffu) : __uint_as_float(~k);
}

// bijective XCD swizzle: round-robin block->XCD dispatch becomes a contiguous
// work range per XCD so its private L2 holds one slab.
__device__ __forceinline__ int xcd_swz(int b, int nwg){
  int q = nwg >> 3, r = nwg & 7;
  int xcd = b & 7, o = b >> 3;
  return (xcd < r ? xcd*(q+1) : r*(q+1) + (xcd-r)*q) + o;
}

__device__ __forceinline__ float blockReduceSum(float v, float* sh){
  int t = threadIdx.x;
  __syncthreads();
  sh[t] = v; __syncthreads();
  for (int o = 128; o > 0; o >>= 1){ if (t < o) sh[t] += sh[t+o]; __syncthreads(); }
  float r = sh[0]; __syncthreads();
  return r;
}
__device__ __forceinline__ float blockReduceMin(float v, float* sh){
  int t = threadIdx.x;
  __syncthreads();
  sh[t] = v; __syncthreads();
  for (int o = 128; o > 0; o >>= 1){ if (t < o) sh[t] = fminf(sh[t], sh[t+o]); __syncthreads(); }
  float r = sh[0]; __syncthreads();
  return r;
}
__device__ __forceinline__ float blockReduceMax(float v, float* sh){
  int t = threadIdx.x;
  __syncthreads();
  sh[t] = v; __syncthreads();
  for (int o = 128; o > 0; o >>= 1){ if (t < o) sh[t] = fmaxf(sh[t], sh[t+o]); __syncthreads(); }
  float r = sh[0]; __syncthreads();
  return r;
}

// ---------------- CCL ----------------

// Round-1 scatter: labels computed from hot in-register; lut written DENSELY
// by lut-position row (8 positions/thread). Proven path (R5/R6), unchanged.
__global__ __launch_bounds__(256) void k_scatter1(const float* __restrict__ hot,
                                                  int* __restrict__ lut){
  int y  = xcd_swz(blockIdx.x, HH);
  int t  = threadIdx.x;
  int x0 = t << 3;                       // first normal pixel col (pixels x0-1..x0+6)
  int P  = (y << 11) + x0;               // first lut position
  int ci = t << 1;                       // aligned int4 col of x0
  int cim = (ci > 0) ? ci - 1 : 0;
  int rows3[3];
  rows3[0] = (y > 0) ? y-1 : 0;
  rows3[1] = y;
  rows3[2] = (y < HH-1) ? y+1 : HH-1;

  int c[3][10];                          // cols x0-2 .. x0+7 per row
  #pragma unroll
  for (int j = 0; j < 3; ++j){
    int rb = rows3[j] << 9;              // int4-row base
    const float4* h4 = (const float4*)hot;
    float4 a = h4[rb + cim], b = h4[rb + ci], d = h4[rb + ci + 1];
    int lb = rows3[j]*WW + (x0 - 2) + 1;      // label of col x0-2
    c[j][0] = (a.z > 0.3f) ? lb   : 0;
    c[j][1] = (a.w > 0.3f) ? lb+1 : 0;
    c[j][2] = (b.x > 0.3f) ? lb+2 : 0;
    c[j][3] = (b.y > 0.3f) ? lb+3 : 0;
    c[j][4] = (b.z > 0.3f) ? lb+4 : 0;
    c[j][5] = (b.w > 0.3f) ? lb+5 : 0;
    c[j][6] = (d.x > 0.3f) ? lb+6 : 0;
    c[j][7] = (d.y > 0.3f) ? lb+7 : 0;
    c[j][8] = (d.z > 0.3f) ? lb+8 : 0;
    c[j][9] = (d.w > 0.3f) ? lb+9 : 0;
    if (t == 0){ c[j][0] = c[j][2]; c[j][1] = c[j][2]; }  // clamp cols -2,-1 -> col 0
  }

  int m[8];
  #pragma unroll
  for (int k = 0; k < 8; ++k){
    int h0 = max(max(c[0][k], c[0][k+1]), c[0][k+2]);
    int h1 = max(max(c[1][k], c[1][k+1]), c[1][k+2]);
    int h2 = max(max(c[2][k], c[2][k+1]), c[2][k+2]);
    m[k] = max(h0, max(h1, h2));
  }

  int val[8];
  #pragma unroll
  for (int k = 0; k < 8; ++k){
    int l = c[1][k+1];                   // center label (pixel col x0-1+k)
    val[k] = l ? m[k] : (P + k);         // m >= l always (window has center)
  }
  if (t == 0){
    if (y == 0) val[0] = 0;              // lut[0] = 0
    else {
      // crossing pixel q = (y-1, 2047): window rows max(y-2,0)..y, cols 2046..2047
      int rr0 = (y >= 2) ? y-2 : 0;
      int rr[3] = {rr0, y-1, y};
      int mm = 0;
      #pragma unroll
      for (int j = 0; j < 3; ++j){
        float ha = hot[rr[j]*WW + 2046], hb = hot[rr[j]*WW + 2047];
        int la  = (ha > 0.3f) ? rr[j]*WW + 2047 : 0;
        int lbv = (hb > 0.3f) ? rr[j]*WW + 2048 : 0;
        mm = max(mm, max(la, lbv));
      }
      bool fgq = hot[(y-1)*WW + 2047] > 0.3f;
      val[0] = fgq ? mm : P;
    }
  }
  *(int4*)(lut + P)     = make_int4(val[0], val[1], val[2], val[3]);
  *(int4*)(lut + P + 4) = make_int4(val[4], val[5], val[6], val[7]);
  if (y == HH-1 && t == 255){
    // position NPIX, pixel (2047,2047): window rows 2046..2047, cols 2046..2047
    int mm = max(max(c[0][8], c[0][9]), max(c[1][8], c[1][9]));
    int l = c[1][9];
    lut[NPIX] = l ? mm : NPIX;
  }
}

// Rounds 2/3 scatter: pixel-framed, LDS-staged. One block per pixel row;
// stage rows y-1,y,y+1 via 6 disjoint coalesced int4 loads/thread; 3x3 max
// from LDS with stride-256 x-assignment (lane-consecutive LDS reads -> 2
// lanes/bank, conflict-free). Rare predicated atomicMax into the carried lut.
// Clamped duplicate rows/cols idempotent under max; labels>=0 matches 0-pad.
__global__ __launch_bounds__(256) void k_scatter23(const int* __restrict__ lab,
                                                   int* __restrict__ lut){
  __shared__ int sh[3*2048];
  int y = xcd_swz(blockIdx.x, HH);
  int t = threadIdx.x;
  int ym = (y > 0) ? y-1 : 0, yp = (y < HH-1) ? y+1 : HH-1;
  const int4* l4 = (const int4*)lab;
  int4* s4 = (int4*)sh;
  s4[t]          = l4[(ym<<9) + t];
  s4[t+256]      = l4[(ym<<9) + t + 256];
  s4[512 + t]    = l4[(y <<9) + t];
  s4[768 + t]    = l4[(y <<9) + t + 256];
  s4[1024 + t]   = l4[(yp<<9) + t];
  s4[1280 + t]   = l4[(yp<<9) + t + 256];
  __syncthreads();
  const int* r0 = sh;
  const int* r1 = sh + 2048;
  const int* r2 = sh + 4096;
  #pragma unroll
  for (int k = 0; k < 8; ++k){
    int x  = t + (k << 8);
    int xm = (x > 0) ? x-1 : 0;
    int xp = (x < WW-1) ? x+1 : WW-1;
    int l  = r1[x];
    int m = max(max(max(r0[xm], r0[x]), max(r0[xp], r1[xm])),
                max(max(r1[x],  r1[xp]),
                    max(max(r2[xm], r2[x]), r2[xp])));
    if (l != 0 && m > l) atomicMax(&lut[l], m);
  }
}

// Materialized composition: dst[i] = src^(HOPS+1)[i], with early exit at
// fixed points (exact: fixed points absorb further applications).
template<int HOPS>
__global__ void k_compress(const int* __restrict__ src, int* __restrict__ dst){
  int wb = xcd_swz(blockIdx.x, gridDim.x);
  int base = (wb*256 + threadIdx.x) * 4;
  if (base + 3 <= NPIX){
    int4 v = *(const int4*)(src + base);
    int j0 = v.x, j1 = v.y, j2 = v.z, j3 = v.w;
    #pragma unroll 1
    for (int k = 0; k < HOPS; ++k){
      int n0 = src[j0], n1 = src[j1], n2 = src[j2], n3 = src[j3];
      bool done = (n0==j0) && (n1==j1) && (n2==j2) && (n3==j3);
      j0 = n0; j1 = n1; j2 = n2; j3 = n3;
      if (done) break;
    }
    *(int4*)(dst + base) = make_int4(j0, j1, j2, j3);
  } else {
    for (int i = base; i <= NPIX; ++i){
      int j = src[i];
      for (int k = 0; k < HOPS; ++k){
        int n = src[j];
        if (n == j) break;
        j = n;
      }
      dst[i] = j;
    }
  }
}

// round-1 apply: lab[p] = fg(p) ? lut[p+1] : 0   (XCD-swizzled so lab slabs
// land in the same XCD that k_scatter23 will read them from)
__global__ void k_apply1(const float* __restrict__ hot, const int* __restrict__ lut,
                         int* __restrict__ lab){
  int t = xcd_swz(blockIdx.x, gridDim.x)*256 + threadIdx.x;
  if (t >= NP4) return;
  float4 h = ((const float4*)hot)[t];
  int4 A = ((const int4*)lut)[t];
  int nb = lut[4*t + 4];                 // t=NP4-1 -> lut[NPIX], valid
  int4 L;
  L.x = (h.x > 0.3f) ? A.y : 0;
  L.y = (h.y > 0.3f) ? A.z : 0;
  L.z = (h.z > 0.3f) ? A.w : 0;
  L.w = (h.w > 0.3f) ? nb  : 0;
  ((int4*)lab)[t] = L;
}

__global__ void k_apply(int* __restrict__ lab, const int* __restrict__ lut){
  int t = xcd_swz(blockIdx.x, gridDim.x)*256 + threadIdx.x;
  if (t >= NP4) return;
  int4 L = ((int4*)lab)[t];
  L.x = lut[L.x]; L.y = lut[L.y]; L.z = lut[L.z]; L.w = lut[L.w];
  ((int4*)lab)[t] = L;
}

// round-3: lab = lut^8[lab] fused as a capped in-register chase (the lut array
// is dead afterwards, so no materialization needed) + presence marking.
__global__ void k_chase_mark(int* __restrict__ lab, const int* __restrict__ lut,
                             unsigned char* __restrict__ presb){
  int t = blockIdx.x*256 + threadIdx.x;
  if (t >= NP4) return;
  int4 L = ((int4*)lab)[t];
  int j0 = L.x, j1 = L.y, j2 = L.z, j3 = L.w;
  #pragma unroll 1
  for (int k = 0; k < 8; ++k){
    int n0 = lut[j0], n1 = lut[j1], n2 = lut[j2], n3 = lut[j3];
    bool done = (n0==j0) && (n1==j1) && (n2==j2) && (n3==j3);
    j0 = n0; j1 = n1; j2 = n2; j3 = n3;
    if (done) break;
  }
  ((int4*)lab)[t] = make_int4(j0, j1, j2, j3);
  presb[j0] = 1; presb[j1] = 1; presb[j2] = 1; presb[j3] = 1;
}

// ---------------- rank relabel (byte presence array) ----------------

__global__ void k_clearb(unsigned char* __restrict__ presb){
  int base = (blockIdx.x*256 + threadIdx.x) * 16;
  if (base + 15 <= NPIX) *(int4*)(presb + base) = make_int4(0,0,0,0);
  else { for (int k = 0; k < 16; ++k){ int idx = base + k; if (idx <= NPIX) presb[idx] = 0; } }
}

__global__ void k_scan1(const unsigned char* __restrict__ presb, int* __restrict__ bsum){
  __shared__ int sh[256];
  int t = threadIdx.x;
  int base = blockIdx.x*4096 + t*16;
  int run = 0;
  if (base + 15 <= NPIX){
    int4 v = *(const int4*)(presb + base);
    run = (int)((((unsigned)v.x & 0x01010101u) * 0x01010101u) >> 24)
        + (int)((((unsigned)v.y & 0x01010101u) * 0x01010101u) >> 24)
        + (int)((((unsigned)v.z & 0x01010101u) * 0x01010101u) >> 24)
        + (int)((((unsigned)v.w & 0x01010101u) * 0x01010101u) >> 24);
  } else {
    for (int k = 0; k < 16; ++k){ int idx = base + k; if (idx <= NPIX) run += presb[idx]; }
  }
  sh[t] = run; __syncthreads();
  for (int o = 128; o > 0; o >>= 1){ if (t < o) sh[t] += sh[t+o]; __syncthreads(); }
  if (t == 0) bsum[blockIdx.x] = sh[0];
}

// block-sum exclusive scan + stats clear (fused)
__global__ void k_scan2(int* __restrict__ bs, int nb, float* __restrict__ st){
  __shared__ int sh[1024];
  int t = threadIdx.x;
  if (t < S_TOT) st[t] = (t >= S_KMINX) ? -0.0f : 0.0f;      // -0.0f bits == encf(0.0f)
  if (t + 1024 < S_TOT) st[t + 1024] = (t + 1024 >= S_KMINX) ? -0.0f : 0.0f;
  int v = (t < nb) ? bs[t] : 0;
  sh[t] = v; __syncthreads();
  for (int o = 1; o < 1024; o <<= 1){
    int add = (t >= o) ? sh[t-o] : 0;
    __syncthreads();
    sh[t] += add;
    __syncthreads();
  }
  if (t < nb) bs[t] = (t == 0) ? 0 : sh[t-1];   // exclusive
  if (t == 1023 && nb > 1024) bs[1024] = sh[1023]; // nb <= 1025 here
}

__global__ void k_scan3(const unsigned char* __restrict__ presb,
                        const int* __restrict__ bsum, int* __restrict__ ranks){
  __shared__ int sh[256];
  int t = threadIdx.x;
  int base = blockIdx.x*4096 + t*16;
  int v[16];
  int run = 0;
  bool vec = (base + 15 <= NPIX);
  if (vec){
    int4 q = *(const int4*)(presb + base);
    unsigned w[4] = {(unsigned)q.x, (unsigned)q.y, (unsigned)q.z, (unsigned)q.w};
    #pragma unroll
    for (int a = 0; a < 4; ++a){
      #pragma unroll
      for (int b = 0; b < 4; ++b){ run += (w[a] >> (8*b)) & 1; v[a*4+b] = run; }
    }
  } else {
    for (int k = 0; k < 16; ++k){
      int idx = base + k;
      int x = (idx <= NPIX) ? presb[idx] : 0;
      run += x; v[k] = run;
    }
  }
  sh[t] = run; __syncthreads();
  for (int o = 1; o < 256; o <<= 1){
    int add = (t >= o) ? sh[t-o] : 0;
    __syncthreads();
    sh[t] += add;
    __syncthreads();
  }
  int offs = bsum[blockIdx.x] + sh[t] - run - 1;   // rank = inclusive cumsum - 1
  if (vec){
    int4* r4 = (int4*)(ranks + base);
    #pragma unroll
    for (int k = 0; k < 4; ++k)
      r4[k] = make_int4(v[4*k]+offs, v[4*k+1]+offs, v[4*k+2]+offs, v[4*k+3]+offs);
  } else {
    for (int k = 0; k < 16; ++k){ int idx = base + k; if (idx <= NPIX) ranks[idx] = v[k] + offs; }
  }
}

// ---------------- per-segment stats ----------------

// fused: segment-id relabel (rank clamp) + first-moment accumulation
__global__ void k_stats1(int* __restrict__ lab, const int* __restrict__ ranks,
                         const float* __restrict__ hot, float* __restrict__ st){
  __shared__ float sh[256];
  float a0 = 0.f, x0 = 0.f, y0 = 0.f, h0 = 0.f;
  int stride = gridDim.x * blockDim.x;
  for (int t = blockIdx.x*blockDim.x + threadIdx.x; t < NP4; t += stride){
    int4 L = ((int4*)lab)[t];
    float4 hq = ((const float4*)hot)[t];
    int p0 = t*4;
    float xb = (float)(p0 & (WW-1));
    float yf = (float)(p0 >> 11);
    int ls[4] = {L.x, L.y, L.z, L.w};
    float hs[4] = {hq.x, hq.y, hq.z, hq.w};
    #pragma unroll
    for (int j = 0; j < 4; ++j){
      int r = ranks[ls[j]];
      int s = (r >= MAXNC) ? 0 : r;
      ls[j] = s;
      float xf = xb + (float)j;
      if (s == 0){ a0 += 1.f; x0 += xf; y0 += yf; h0 += hs[j]; }
      else {
        atomicAdd(&st[S_AREA+s], 1.f);
        atomicAdd(&st[S_SX+s], xf);
        atomicAdd(&st[S_SY+s], yf);
        atomicAdd(&st[S_SHOT+s], hs[j]);
      }
    }
    ((int4*)lab)[t] = make_int4(ls[0], ls[1], ls[2], ls[3]);
  }
  a0 = blockReduceSum(a0, sh);
  x0 = blockReduceSum(x0, sh);
  y0 = blockReduceSum(y0, sh);
  h0 = blockReduceSum(h0, sh);
  if (threadIdx.x == 0){
    atomicAdd(&st[S_AREA], a0);
    atomicAdd(&st[S_SX], x0);
    atomicAdd(&st[S_SY], y0);
    atomicAdd(&st[S_SHOT], h0);
  }
}

__global__ void k_mu(float* __restrict__ st){
  int s = threadIdx.x;
  if (s < MAXNC){
    float a = st[S_AREA+s];
    st[S_MUX+s] = st[S_SX+s] / a;   // 0/0 -> NaN matches ref
    st[S_MUY+s] = st[S_SY+s] / a;
  }
}

__global__ void k_stats2(const int* __restrict__ lab, float* __restrict__ st){
  __shared__ float sh[256];
  float xx0 = 0.f, xy0 = 0.f, yy0 = 0.f;
  int stride = gridDim.x * blockDim.x;
  for (int t = blockIdx.x*blockDim.x + threadIdx.x; t < NP4; t += stride){
    int4 L = ((int4*)lab)[t];
    int p0 = t*4;
    float xb = (float)(p0 & (WW-1));
    float yf = (float)(p0 >> 11);
    int ls[4] = {L.x, L.y, L.z, L.w};
    #pragma unroll
    for (int j = 0; j < 4; ++j){
      int s = ls[j];
      float cx = xb + (float)j - st[S_MUX+s];
      float cy = yf - st[S_MUY+s];
      float pxx = cx*cx, pxy = cx*cy, pyy = cy*cy;
      if (s == 0){ xx0 += pxx; xy0 += pxy; yy0 += pyy; }
      else {
        atomicAdd(&st[S_CXX+s], pxx);
        atomicAdd(&st[S_CXY+s], pxy);
        atomicAdd(&st[S_CYY+s], pyy);
      }
    }
  }
  xx0 = blockReduceSum(xx0, sh);
  xy0 = blockReduceSum(xy0, sh);
  yy0 = blockReduceSum(yy0, sh);
  if (threadIdx.x == 0){
    atomicAdd(&st[S_CXX], xx0);
    atomicAdd(&st[S_CXY], xy0);
    atomicAdd(&st[S_CYY], yy0);
  }
}

__global__ void k_svd(float* __restrict__ st){
  int s = threadIdx.x;
  if (s >= MAXNC) return;
  float a = st[S_AREA+s];
  float vx  = st[S_CXX+s] / a;
  float vxy = st[S_CXY+s] / a;
  float vy  = st[S_CYY+s] / a;
  float theta = 0.5f * atan2f(2.0f*vxy, vx - vy);
  float c = cosf(theta), sn = sinf(theta);
  float tr = vx + vy;
  float d = (vx - vy)*(vx - vy) + 4.0f*vxy*vxy;
  float disc = fmaxf(d, 1e-12f);
  float sq = sqrtf(disc);
  float l2 = fmaxf((tr - sq)*0.5f, 0.0f);
  float margin = sqrtf(sqrtf(l2)) * 4.0f;   // sqrt(l[:,1]) * 4 * MAR, l = sqrt(eig)
  st[S_RC+s] = c;
  st[S_RS+s] = sn;
  st[S_MG+s] = margin;
}

__global__ void k_stats3(const int* __restrict__ lab, float* __restrict__ st){
  __shared__ float sh[256];
  unsigned int* ku = (unsigned int*)st;
  float mnx =  INFINITY, mxx = -INFINITY, mny =  INFINITY, mxy = -INFINITY;
  int stride = gridDim.x * blockDim.x;
  for (int t = blockIdx.x*blockDim.x + threadIdx.x; t < NP4; t += stride){
    int4 L = ((int4*)lab)[t];
    int p0 = t*4;
    float xb = (float)(p0 & (WW-1));
    float yf = (float)(p0 >> 11);
    int ls[4] = {L.x, L.y, L.z, L.w};
    #pragma unroll
    for (int j = 0; j < 4; ++j){
      int s = ls[j];
      float cx = xb + (float)j - st[S_MUX+s];
      float cy = yf - st[S_MUY+s];
      float c = st[S_RC+s], sn = st[S_RS+s];
      float rx =  c*cx + sn*cy;   // m^T @ coords
      float ry = -sn*cx + c*cy;
      if (s == 0){
        mnx = fminf(mnx, rx); mxx = fmaxf(mxx, rx);
        mny = fminf(mny, ry); mxy = fmaxf(mxy, ry);
      } else {
        atomicMin(&ku[S_KMINX+s], encf(rx));
        atomicMax(&ku[S_KMAXX+s], encf(rx));
        atomicMin(&ku[S_KMINY+s], encf(ry));
        atomicMax(&ku[S_KMAXY+s], encf(ry));
      }
    }
  }
  mnx = blockReduceMin(mnx, sh);
  mxx = blockReduceMax(mxx, sh);
  mny = blockReduceMin(mny, sh);
  mxy = blockReduceMax(mxy, sh);
  if (threadIdx.x == 0){
    atomicMin(&ku[S_KMINX], encf(mnx));
    atomicMax(&ku[S_KMAXX], encf(mxx));
    atomicMin(&ku[S_KMINY], encf(mny));
    atomicMax(&ku[S_KMAXY], encf(mxy));
  }
}

__global__ void k_final(const float* __restrict__ st, const float* __restrict__ scale, float* __restrict__ out){
  int s = threadIdx.x;
  if (s >= MAXNC) return;
  const unsigned int* ku = (const unsigned int*)st;
  float a   = st[S_AREA+s];
  float lvl = st[S_SHOT+s];
  float mg  = st[S_MG+s];
  float minx = decf(ku[S_KMINX+s]) - mg;   // key init enc(0) == clamp vs 0
  float maxx = decf(ku[S_KMAXX+s]) + mg;
  float miny = decf(ku[S_KMINY+s]) - mg;
  float maxy = decf(ku[S_KMAXY+s]) + mg;
  bool ok = (lvl/a > 0.7f) && (maxx - minx > 5.0f) && (maxy - miny > 5.0f);  // NaN -> false
  float c = st[S_RC+s], sn = st[S_RS+s];
  float mux = st[S_MUX+s], muy = st[S_MUY+s];
  float sc2 = scale[0] * 2.0f;
  float rxs[5] = {minx, maxx, maxx, minx, minx};
  float rys[5] = {miny, miny, maxy, maxy, miny};
  #pragma unroll
  for (int k = 0; k < 5; ++k){
    float X = c*rxs[k] - sn*rys[k] + mux;   // m @ rec + mu
    float Y = sn*rxs[k] + c*rys[k] + muy;
    out[s*10 + 2*k + 0] = ok ? X * sc2 : 0.0f;
    out[s*10 + 2*k + 1] = ok ? Y * sc2 : 0.0f;
  }
}

// ---------------- host ----------------

extern "C" void kernel_launch(void* const* d_in, const int* in_sizes, int n_in,
                              void* d_out, int out_size, void* d_ws, size_t ws_size,
                              hipStream_t stream) {
  const float* hot   = (const float*)d_in[0];
  const float* scale = (const float*)d_in[1];
  float* out = (float*)d_out;

  char* ws = (char*)d_ws;
  size_t off = 0;
  int* lab  = (int*)(ws + off); off += (size_t)NPIX * 4;
  int* lutA = (int*)(ws + off); off += (size_t)(NPIX + 64) * 4;
  int* lutB = (int*)(ws + off); off += (size_t)(NPIX + 64) * 4;
  int* bsum = (int*)(ws + off); off += 2048 * 4;
  float* st = (float*)(ws + off); off += S_TOT * 4;

  dim3 B(256);
  int g4  = (NP4 + 255) / 256;          // 4096  — NP4-range kernels
  int g4t = (NP4 + 256) / 256;          // 4097  — NP4+1 threads (tail element)
  int NB  = (NPIX + 1 + 4095) / 4096;   // 1025  — scan/clear blocks

  int* cur = lutA;
  int* alt = lutB;

  // round 1: dense scatter from hot, then lut^4096 = (^4)^6 exact
  k_scatter1<<<HH, B, 0, stream>>>(hot, cur);
  for (int i = 0; i < 6; ++i){
    k_compress<3><<<g4t, B, 0, stream>>>(cur, alt);
    int* tp = cur; cur = alt; alt = tp;
  }                                      // cur = lutA
  k_apply1<<<g4, B, 0, stream>>>(hot, cur, lab);

  // round 2: LDS-staged scatter (carried lut) + ^64 = (^4)^3 exact, materialized
  k_scatter23<<<HH, B, 0, stream>>>(lab, cur);
  for (int i = 0; i < 3; ++i){
    k_compress<3><<<g4t, B, 0, stream>>>(cur, alt);
    int* tp = cur; cur = alt; alt = tp;
  }                                      // cur = lutB; lutA dead
  unsigned char* presb = (unsigned char*)alt;   // alt == lutA (dead) -> presence bytes
  k_clearb<<<NB, B, 0, stream>>>(presb);
  k_apply<<<g4, B, 0, stream>>>(lab, cur);

  // round 3: LDS-staged scatter + fused ^8 chase-apply + presence marking
  k_scatter23<<<HH, B, 0, stream>>>(lab, cur);
  k_chase_mark<<<g4, B, 0, stream>>>(lab, cur, presb);

  // rank relabel over byte presence; ranks reuse the dead lut (cur)
  int* ranks = cur;
  k_scan1<<<NB, B, 0, stream>>>(presb, bsum);
  k_scan2<<<1, 1024, 0, stream>>>(bsum, NB, st);   // + stats clear
  k_scan3<<<NB, B, 0, stream>>>(presb, bsum, ranks);

  // per-segment stats (seg relabel fused into stats1)
  k_stats1<<<2048, B, 0, stream>>>(lab, ranks, hot, st);
  k_mu<<<1, 128, 0, stream>>>(st);
  k_stats2<<<2048, B, 0, stream>>>(lab, st);
  k_svd<<<1, 128, 0, stream>>>(st);
  k_stats3<<<2048, B, 0, stream>>>(lab, st);
  k_final<<<1, 128, 0, stream>>>(st, scale, out);
}